// Round 1
// baseline (1115.058 us; speedup 1.0000x reference)
//
#include <hip/hip_runtime.h>

#define N_NODES   100000
#define N_EDGES   1600000
#define HID       64
#define NUM_GRAPHS 128
#define BN_EPS    1e-5f
#define NBLK_SCAN 391   // ceil(N_NODES/256)

// ---------------- CSR build ----------------

__global__ void k_deg(const int* __restrict__ dst, int* __restrict__ deg) {
  int i = blockIdx.x * blockDim.x + threadIdx.x;
  int stride = gridDim.x * blockDim.x;
  for (; i < N_EDGES; i += stride) atomicAdd(&deg[dst[i]], 1);
}

__global__ void k_scan_block(const int* __restrict__ deg, int* __restrict__ off,
                             int* __restrict__ bsum) {
  __shared__ int s[256];
  int b = blockIdx.x, t = threadIdx.x;
  int i = b * 256 + t;
  int v = (i < N_NODES) ? deg[i] : 0;
  s[t] = v;
  __syncthreads();
  for (int d = 1; d < 256; d <<= 1) {
    int x = (t >= d) ? s[t - d] : 0;
    __syncthreads();
    s[t] += x;
    __syncthreads();
  }
  if (i < N_NODES) off[i + 1] = s[t];   // block-local inclusive
  if (t == 255) bsum[b] = s[255];
}

__global__ void k_scan_tops(int* __restrict__ bsum) {
  __shared__ int s[512];
  int t = threadIdx.x;
  int v = (t < NBLK_SCAN) ? bsum[t] : 0;
  s[t] = v;
  __syncthreads();
  for (int d = 1; d < 512; d <<= 1) {
    int x = (t >= d) ? s[t - d] : 0;
    __syncthreads();
    s[t] += x;
    __syncthreads();
  }
  if (t < NBLK_SCAN) bsum[t] = s[t] - v;  // exclusive over block sums
}

__global__ void k_scan_add(const int* __restrict__ deg, int* __restrict__ off,
                           const int* __restrict__ bsum, int* __restrict__ cur) {
  int b = blockIdx.x, t = threadIdx.x;
  int i = b * 256 + t;
  if (i >= N_NODES) return;
  int fin = off[i + 1] + bsum[b];
  off[i + 1] = fin;
  cur[i] = fin - deg[i];  // start position of node i's edge slots
  if (i == 0) off[0] = 0;
}

__global__ void k_fill(const int* __restrict__ src, const int* __restrict__ dst,
                       int* __restrict__ cur, int* __restrict__ esrc) {
  int i = blockIdx.x * blockDim.x + threadIdx.x;
  int stride = gridDim.x * blockDim.x;
  for (; i < N_EDGES; i += stride) {
    int pos = atomicAdd(&cur[dst[i]], 1);
    esrc[pos] = src[i];
  }
}

// ---------------- per-layer kernels ----------------

// one wave per node, lane = feature; pull-gather, no atomics
__global__ void k_gather(const float* __restrict__ X, const int* __restrict__ off,
                         const int* __restrict__ esrc, float* __restrict__ agg) {
  int gid = blockIdx.x * blockDim.x + threadIdx.x;
  int w = gid >> 6;
  int t = gid & 63;
  if (w >= N_NODES) return;
  int s0 = off[w], s1 = off[w + 1];
  float acc = 0.f;
  int i = s0;
  for (; i + 4 <= s1; i += 4) {
    int a = esrc[i], b = esrc[i + 1], c = esrc[i + 2], d = esrc[i + 3];
    float va = X[a * HID + t];
    float vb = X[b * HID + t];
    float vc = X[c * HID + t];
    float vd = X[d * HID + t];
    acc += va + vb + vc + vd;
  }
  for (; i < s1; ++i) acc += X[esrc[i] * HID + t];
  agg[w * HID + t] = acc;
}

// thread-per-node fused 2-layer MLP; weights are wave-uniform (scalar loads)
// NOTE: AGG and OUT may alias (in-place) -> no __restrict__ on them.
__global__ __launch_bounds__(256, 2) void k_mlp(
    const float* __restrict__ X, const float* AGG,
    const float* __restrict__ w1, const float* __restrict__ b1,
    const float* __restrict__ w2, const float* __restrict__ b2,
    float* OUT) {
  int n = blockIdx.x * blockDim.x + threadIdx.x;
  if (n >= N_NODES) return;
  const float* xr = X + n * HID;
  const float* ar = AGG + n * HID;
  float h[HID];
#pragma unroll
  for (int k = 0; k < HID; k += 4) {
    float4 a = *(const float4*)(xr + k);
    float4 g = *(const float4*)(ar + k);
    h[k] = a.x + g.x; h[k + 1] = a.y + g.y; h[k + 2] = a.z + g.z; h[k + 3] = a.w + g.w;
  }
  float hid[HID];
#pragma unroll
  for (int j = 0; j < HID; ++j) hid[j] = b1[j];
#pragma unroll
  for (int k = 0; k < HID; ++k) {
    const float* wr = w1 + k * HID;
#pragma unroll
    for (int j = 0; j < HID; ++j) hid[j] = fmaf(h[k], wr[j], hid[j]);
  }
#pragma unroll
  for (int j = 0; j < HID; ++j) hid[j] = fmaxf(hid[j], 0.f);
  float o[HID];
#pragma unroll
  for (int j = 0; j < HID; ++j) o[j] = b2[j];
#pragma unroll
  for (int k = 0; k < HID; ++k) {
    const float* wr = w2 + k * HID;
#pragma unroll
    for (int j = 0; j < HID; ++j) o[j] = fmaf(hid[k], wr[j], o[j]);
  }
  float* orow = OUT + n * HID;
#pragma unroll
  for (int j = 0; j < HID; j += 4) {
    float4 v; v.x = o[j]; v.y = o[j + 1]; v.z = o[j + 2]; v.w = o[j + 3];
    *(float4*)(orow + j) = v;
  }
}

// column sums / sumsq: wave per row-walker, lane = feature (coalesced)
__global__ void k_stats(const float* __restrict__ H, float* __restrict__ stats) {
  int f = threadIdx.x & 63;
  float s = 0.f, q = 0.f;
  int walker = (blockIdx.x * blockDim.x + threadIdx.x) >> 6;
  int stride = (gridDim.x * blockDim.x) >> 6;
  for (int n = walker; n < N_NODES; n += stride) {
    float v = H[n * HID + f];
    s += v; q += v * v;
  }
  __shared__ float ls[256], lq[256];
  ls[threadIdx.x] = s; lq[threadIdx.x] = q;
  __syncthreads();
  if (threadIdx.x < 64) {
    s = ls[threadIdx.x] + ls[64 + threadIdx.x] + ls[128 + threadIdx.x] + ls[192 + threadIdx.x];
    q = lq[threadIdx.x] + lq[64 + threadIdx.x] + lq[128 + threadIdx.x] + lq[192 + threadIdx.x];
    atomicAdd(&stats[f], s);
    atomicAdd(&stats[64 + f], q);
  }
}

// scale/shift from accumulated sums; sc[0..63]=scale, sc[64..127]=shift
__global__ void k_bnparams(const float* __restrict__ stats, float* __restrict__ sc,
                           const float* __restrict__ gamma, const float* __restrict__ beta) {
  int t = threadIdx.x;
  float mean = stats[t] * (1.0f / N_NODES);
  float var = stats[64 + t] * (1.0f / N_NODES) - mean * mean;
  float scale = gamma[t] * rsqrtf(var + BN_EPS);
  sc[t] = scale;
  sc[64 + t] = beta[t] - mean * scale;
}

// elementwise BN + ReLU (may run in place: H==Y, same element per thread)
__global__ void k_bnrelu(const float* H, const float* __restrict__ sc, float* Y) {
  __shared__ float ssc[64], ssh[64];
  if (threadIdx.x < 64) { ssc[threadIdx.x] = sc[threadIdx.x]; ssh[threadIdx.x] = sc[64 + threadIdx.x]; }
  __syncthreads();
  int i = blockIdx.x * blockDim.x + threadIdx.x;   // exact grid: N_NODES*16 threads
  int f = (i & 15) << 2;
  float4 v = ((const float4*)H)[i];
  v.x = fmaxf(fmaf(v.x, ssc[f + 0], ssh[f + 0]), 0.f);
  v.y = fmaxf(fmaf(v.y, ssc[f + 1], ssh[f + 1]), 0.f);
  v.z = fmaxf(fmaf(v.z, ssc[f + 2], ssh[f + 2]), 0.f);
  v.w = fmaxf(fmaf(v.w, ssc[f + 3], ssh[f + 3]), 0.f);
  ((float4*)Y)[i] = v;
}

// ---------------- pooling + head ----------------

__global__ void k_count(const int* __restrict__ batch, float* __restrict__ pcnt) {
  int n = blockIdx.x * blockDim.x + threadIdx.x;
  if (n < N_NODES) atomicAdd(&pcnt[batch[n]], 1.0f);
}

// thread per (node, 4-feature chunk); wave combines 4 nodes when same graph
__global__ void k_pool(const float* __restrict__ H, const int* __restrict__ batch,
                       float* __restrict__ psum) {
  int i = blockIdx.x * blockDim.x + threadIdx.x;  // exact grid: N_NODES*16
  int n = i >> 4, c = (i & 15) << 2;
  int b = batch[n];
  float4 v = *(const float4*)(H + n * HID + c);
  int lane = threadIdx.x & 63;
  int bfirst = __shfl(b, lane & 15);
  bool same = __all(b == bfirst);
  if (same) {
    v.x += __shfl_xor(v.x, 16); v.y += __shfl_xor(v.y, 16);
    v.z += __shfl_xor(v.z, 16); v.w += __shfl_xor(v.w, 16);
    v.x += __shfl_xor(v.x, 32); v.y += __shfl_xor(v.y, 32);
    v.z += __shfl_xor(v.z, 32); v.w += __shfl_xor(v.w, 32);
    if (lane < 16) {
      float* p = psum + b * HID + c;
      atomicAdd(p + 0, v.x); atomicAdd(p + 1, v.y);
      atomicAdd(p + 2, v.z); atomicAdd(p + 3, v.w);
    }
  } else {
    float* p = psum + b * HID + c;
    atomicAdd(p + 0, v.x); atomicAdd(p + 1, v.y);
    atomicAdd(p + 2, v.z); atomicAdd(p + 3, v.w);
  }
}

__global__ void k_final(const float* __restrict__ psum, const float* __restrict__ pcnt,
                        const float* __restrict__ fw1, const float* __restrict__ fb1,
                        const float* __restrict__ fw2, const float* __restrict__ fb2,
                        float* __restrict__ out) {
  int g = blockIdx.x, t = threadIdx.x;
  __shared__ float row[64];
  float cnt = fmaxf(pcnt[g], 1.0f);
  row[t] = psum[g * HID + t] / cnt;
  __syncthreads();
  float acc = fb1[t];
  for (int k = 0; k < HID; ++k) acc = fmaf(row[k], fw1[k * HID + t], acc);
  float h = fmaxf(acc, 0.f);
  float v = h * fw2[t];
  for (int o = 32; o > 0; o >>= 1) v += __shfl_down(v, o);
  if (t == 0) out[g] = fmaxf(v + fb2[0], 0.f);
}

// ---------------- launch ----------------

extern "C" void kernel_launch(void* const* d_in, const int* in_sizes, int n_in,
                              void* d_out, int out_size, void* d_ws, size_t ws_size,
                              hipStream_t stream) {
  const float* x     = (const float*)d_in[0];
  const int*   ei    = (const int*)d_in[1];
  const int*   batch = (const int*)d_in[2];
  const int* esrc_in = ei;
  const int* edst_in = ei + N_EDGES;

  const float* w1[3], * b1[3], * w2[3], * b2[3], * gg[3], * bt[3];
  for (int l = 0; l < 3; ++l) {
    w1[l] = (const float*)d_in[3 + 6 * l];
    b1[l] = (const float*)d_in[4 + 6 * l];
    w2[l] = (const float*)d_in[5 + 6 * l];
    b2[l] = (const float*)d_in[6 + 6 * l];
    gg[l] = (const float*)d_in[7 + 6 * l];
    bt[l] = (const float*)d_in[8 + 6 * l];
  }
  const float* fw1 = (const float*)d_in[21];
  const float* fb1 = (const float*)d_in[22];
  const float* fw2 = (const float*)d_in[23];
  const float* fb2 = (const float*)d_in[24];

  char* p = (char*)d_ws;
  float* bufA  = (float*)p;                 p += (size_t)N_NODES * HID * 4;   // 25.6 MB
  float* bufB  = (float*)p;                 p += (size_t)N_NODES * HID * 4;   // 25.6 MB
  int*   esrc  = (int*)p;                   p += (size_t)N_EDGES * 4;         // 6.4 MB
  int*   deg   = (int*)p;                   p += (size_t)N_NODES * 4;
  int*   off   = (int*)p;                   p += 400016;                      // N_NODES+1 ints
  int*   cur   = (int*)p;                   p += (size_t)N_NODES * 4;
  int*   bsum  = (int*)p;                   p += 2048;
  float* stats = (float*)p;                 p += 1024;                        // sums(128) + scale/shift(128)
  float* psum  = (float*)p;                 p += (size_t)NUM_GRAPHS * HID * 4;
  float* pcnt  = (float*)p;                 p += 512;
  (void)ws_size; (void)in_sizes; (void)n_in; (void)out_size;

  // ---- CSR build (once per call) ----
  hipMemsetAsync(deg, 0, (size_t)N_NODES * 4, stream);
  k_deg<<<2048, 256, 0, stream>>>(edst_in, deg);
  k_scan_block<<<NBLK_SCAN, 256, 0, stream>>>(deg, off, bsum);
  k_scan_tops<<<1, 512, 0, stream>>>(bsum);
  k_scan_add<<<NBLK_SCAN, 256, 0, stream>>>(deg, off, bsum, cur);
  k_fill<<<2048, 256, 0, stream>>>(esrc_in, edst_in, cur, esrc);

  // ---- 3 GIN layers ----
  const float* Xs[3] = { x, bufA, bufB };
  float*       Os[3] = { bufA, bufB, bufA };
  for (int l = 0; l < 3; ++l) {
    k_gather<<<N_NODES * 64 / 256, 256, 0, stream>>>(Xs[l], off, esrc, Os[l]);
    k_mlp<<<(N_NODES + 255) / 256, 256, 0, stream>>>(Xs[l], Os[l], w1[l], b1[l], w2[l], b2[l], Os[l]);
    hipMemsetAsync(stats, 0, 128 * 4, stream);
    k_stats<<<512, 256, 0, stream>>>(Os[l], stats);
    k_bnparams<<<1, 64, 0, stream>>>(stats, stats + 128, gg[l], bt[l]);
    k_bnrelu<<<N_NODES * 16 / 256, 256, 0, stream>>>(Os[l], stats + 128, Os[l]);
  }

  // ---- pool + head ----
  hipMemsetAsync(psum, 0, ((size_t)NUM_GRAPHS * HID + NUM_GRAPHS) * 4, stream);
  k_count<<<(N_NODES + 255) / 256, 256, 0, stream>>>(batch, pcnt);
  k_pool<<<N_NODES * 16 / 256, 256, 0, stream>>>(Os[2], batch, psum);
  k_final<<<NUM_GRAPHS, 64, 0, stream>>>(psum, pcnt, fw1, fb1, fw2, fb2, (float*)d_out);
}

// Round 2
// 787.813 us; speedup vs baseline: 1.4154x; 1.4154x over previous
//
#include <hip/hip_runtime.h>

#define N_NODES   100000
#define N_EDGES   1600000
#define HID       64
#define NUM_GRAPHS 128
#define BN_EPS    1e-5f
#define NBLK_SCAN 391   // ceil(N_NODES/256)

// ---------------- CSR build ----------------

__global__ void k_deg(const int* __restrict__ dst, int* __restrict__ deg) {
  int i = blockIdx.x * blockDim.x + threadIdx.x;
  int stride = gridDim.x * blockDim.x;
  for (; i < N_EDGES; i += stride) atomicAdd(&deg[dst[i]], 1);
}

__global__ void k_scan_block(const int* __restrict__ deg, int* __restrict__ off,
                             int* __restrict__ bsum) {
  __shared__ int s[256];
  int b = blockIdx.x, t = threadIdx.x;
  int i = b * 256 + t;
  int v = (i < N_NODES) ? deg[i] : 0;
  s[t] = v;
  __syncthreads();
  for (int d = 1; d < 256; d <<= 1) {
    int x = (t >= d) ? s[t - d] : 0;
    __syncthreads();
    s[t] += x;
    __syncthreads();
  }
  if (i < N_NODES) off[i + 1] = s[t];   // block-local inclusive
  if (t == 255) bsum[b] = s[255];
}

__global__ void k_scan_tops(int* __restrict__ bsum) {
  __shared__ int s[512];
  int t = threadIdx.x;
  int v = (t < NBLK_SCAN) ? bsum[t] : 0;
  s[t] = v;
  __syncthreads();
  for (int d = 1; d < 512; d <<= 1) {
    int x = (t >= d) ? s[t - d] : 0;
    __syncthreads();
    s[t] += x;
    __syncthreads();
  }
  if (t < NBLK_SCAN) bsum[t] = s[t] - v;  // exclusive over block sums
}

__global__ void k_scan_add(const int* __restrict__ deg, int* __restrict__ off,
                           const int* __restrict__ bsum, int* __restrict__ cur) {
  int b = blockIdx.x, t = threadIdx.x;
  int i = b * 256 + t;
  if (i >= N_NODES) return;
  int fin = off[i + 1] + bsum[b];
  off[i + 1] = fin;
  cur[i] = fin - deg[i];  // start position of node i's edge slots
  if (i == 0) off[0] = 0;
}

__global__ void k_fill(const int* __restrict__ src, const int* __restrict__ dst,
                       int* __restrict__ cur, int* __restrict__ esrc) {
  int i = blockIdx.x * blockDim.x + threadIdx.x;
  int stride = gridDim.x * blockDim.x;
  for (; i < N_EDGES; i += stride) {
    int pos = atomicAdd(&cur[dst[i]], 1);
    esrc[pos] = src[i];
  }
}

// ---------------- per-layer kernels ----------------

// one wave per node, lane = feature; pull-gather, no atomics
__global__ void k_gather(const float* __restrict__ X, const int* __restrict__ off,
                         const int* __restrict__ esrc, float* __restrict__ agg) {
  int gid = blockIdx.x * blockDim.x + threadIdx.x;
  int w = gid >> 6;
  int t = gid & 63;
  if (w >= N_NODES) return;
  int s0 = off[w], s1 = off[w + 1];
  float acc = 0.f;
  int i = s0;
  for (; i + 4 <= s1; i += 4) {
    int a = esrc[i], b = esrc[i + 1], c = esrc[i + 2], d = esrc[i + 3];
    float va = X[a * HID + t];
    float vb = X[b * HID + t];
    float vc = X[c * HID + t];
    float vd = X[d * HID + t];
    acc += va + vb + vc + vd;
  }
  for (; i < s1; ++i) acc += X[esrc[i] * HID + t];
  agg[w * HID + t] = acc;
}

// thread-per-node fused 2-layer MLP; weights are wave-uniform (scalar loads)
// NOTE: AGG and OUT may alias (in-place) -> no __restrict__ on them.
__global__ __launch_bounds__(256, 2) void k_mlp(
    const float* __restrict__ X, const float* AGG,
    const float* __restrict__ w1, const float* __restrict__ b1,
    const float* __restrict__ w2, const float* __restrict__ b2,
    float* OUT) {
  int n = blockIdx.x * blockDim.x + threadIdx.x;
  if (n >= N_NODES) return;
  const float* xr = X + n * HID;
  const float* ar = AGG + n * HID;
  float h[HID];
#pragma unroll
  for (int k = 0; k < HID; k += 4) {
    float4 a = *(const float4*)(xr + k);
    float4 g = *(const float4*)(ar + k);
    h[k] = a.x + g.x; h[k + 1] = a.y + g.y; h[k + 2] = a.z + g.z; h[k + 3] = a.w + g.w;
  }
  float hid[HID];
#pragma unroll
  for (int j = 0; j < HID; ++j) hid[j] = b1[j];
#pragma unroll
  for (int k = 0; k < HID; ++k) {
    const float* wr = w1 + k * HID;
#pragma unroll
    for (int j = 0; j < HID; ++j) hid[j] = fmaf(h[k], wr[j], hid[j]);
  }
#pragma unroll
  for (int j = 0; j < HID; ++j) hid[j] = fmaxf(hid[j], 0.f);
  float o[HID];
#pragma unroll
  for (int j = 0; j < HID; ++j) o[j] = b2[j];
#pragma unroll
  for (int k = 0; k < HID; ++k) {
    const float* wr = w2 + k * HID;
#pragma unroll
    for (int j = 0; j < HID; ++j) o[j] = fmaf(hid[k], wr[j], o[j]);
  }
  float* orow = OUT + n * HID;
#pragma unroll
  for (int j = 0; j < HID; j += 4) {
    float4 v; v.x = o[j]; v.y = o[j + 1]; v.z = o[j + 2]; v.w = o[j + 3];
    *(float4*)(orow + j) = v;
  }
}

// column sums / sumsq: wave per row-walker, lane = feature (coalesced)
__global__ void k_stats(const float* __restrict__ H, float* __restrict__ stats) {
  int f = threadIdx.x & 63;
  float s = 0.f, q = 0.f;
  int walker = (blockIdx.x * blockDim.x + threadIdx.x) >> 6;
  int stride = (gridDim.x * blockDim.x) >> 6;
  for (int n = walker; n < N_NODES; n += stride) {
    float v = H[n * HID + f];
    s += v; q += v * v;
  }
  __shared__ float ls[256], lq[256];
  ls[threadIdx.x] = s; lq[threadIdx.x] = q;
  __syncthreads();
  if (threadIdx.x < 64) {
    s = ls[threadIdx.x] + ls[64 + threadIdx.x] + ls[128 + threadIdx.x] + ls[192 + threadIdx.x];
    q = lq[threadIdx.x] + lq[64 + threadIdx.x] + lq[128 + threadIdx.x] + lq[192 + threadIdx.x];
    atomicAdd(&stats[f], s);
    atomicAdd(&stats[64 + f], q);
  }
}

// scale/shift from accumulated sums; sc[0..63]=scale, sc[64..127]=shift
__global__ void k_bnparams(const float* __restrict__ stats, float* __restrict__ sc,
                           const float* __restrict__ gamma, const float* __restrict__ beta) {
  int t = threadIdx.x;
  float mean = stats[t] * (1.0f / N_NODES);
  float var = stats[64 + t] * (1.0f / N_NODES) - mean * mean;
  float scale = gamma[t] * rsqrtf(var + BN_EPS);
  sc[t] = scale;
  sc[64 + t] = beta[t] - mean * scale;
}

// elementwise BN + ReLU (may run in place: H==Y, same element per thread)
__global__ void k_bnrelu(const float* H, const float* __restrict__ sc, float* Y) {
  __shared__ float ssc[64], ssh[64];
  if (threadIdx.x < 64) { ssc[threadIdx.x] = sc[threadIdx.x]; ssh[threadIdx.x] = sc[64 + threadIdx.x]; }
  __syncthreads();
  int i = blockIdx.x * blockDim.x + threadIdx.x;   // exact grid: N_NODES*16 threads
  int f = (i & 15) << 2;
  float4 v = ((const float4*)H)[i];
  v.x = fmaxf(fmaf(v.x, ssc[f + 0], ssh[f + 0]), 0.f);
  v.y = fmaxf(fmaf(v.y, ssc[f + 1], ssh[f + 1]), 0.f);
  v.z = fmaxf(fmaf(v.z, ssc[f + 2], ssh[f + 2]), 0.f);
  v.w = fmaxf(fmaf(v.w, ssc[f + 3], ssh[f + 3]), 0.f);
  ((float4*)Y)[i] = v;
}

// ---------------- pooling + head (batch is SORTED -> segment boundaries) ----------------

// gstart[g] = first node index with batch[i] >= g ; gstart[NUM_GRAPHS] = N_NODES
__global__ void k_bounds(const int* __restrict__ batch, int* __restrict__ gstart) {
  int g = threadIdx.x;
  if (g > NUM_GRAPHS) return;
  int lo = 0, hi = N_NODES;
  while (lo < hi) {
    int mid = (lo + hi) >> 1;
    if (batch[mid] < g) lo = mid + 1; else hi = mid;
  }
  gstart[g] = lo;
}

// one block per graph: coalesced segment mean, no atomics
__global__ void k_pool2(const float* __restrict__ H, const int* __restrict__ gstart,
                        float* __restrict__ pooled) {
  int g = blockIdx.x;
  int s0 = gstart[g], s1 = gstart[g + 1];
  int wv = threadIdx.x >> 6, lane = threadIdx.x & 63;
  float acc = 0.f;
  for (int n = s0 + wv; n < s1; n += 4) acc += H[n * HID + lane];
  __shared__ float ls[256];
  ls[threadIdx.x] = acc;
  __syncthreads();
  if (threadIdx.x < 64) {
    float v = ls[threadIdx.x] + ls[64 + threadIdx.x] + ls[128 + threadIdx.x] + ls[192 + threadIdx.x];
    float cnt = fmaxf((float)(s1 - s0), 1.0f);
    pooled[g * HID + threadIdx.x] = v / cnt;
  }
}

__global__ void k_final(const float* __restrict__ pooled,
                        const float* __restrict__ fw1, const float* __restrict__ fb1,
                        const float* __restrict__ fw2, const float* __restrict__ fb2,
                        float* __restrict__ out) {
  int g = blockIdx.x, t = threadIdx.x;
  __shared__ float row[64];
  row[t] = pooled[g * HID + t];
  __syncthreads();
  float acc = fb1[t];
  for (int k = 0; k < HID; ++k) acc = fmaf(row[k], fw1[k * HID + t], acc);
  float h = fmaxf(acc, 0.f);
  float v = h * fw2[t];
  for (int o = 32; o > 0; o >>= 1) v += __shfl_down(v, o);
  if (t == 0) out[g] = fmaxf(v + fb2[0], 0.f);
}

// ---------------- launch ----------------

extern "C" void kernel_launch(void* const* d_in, const int* in_sizes, int n_in,
                              void* d_out, int out_size, void* d_ws, size_t ws_size,
                              hipStream_t stream) {
  const float* x     = (const float*)d_in[0];
  const int*   ei    = (const int*)d_in[1];
  const int*   batch = (const int*)d_in[2];
  const int* esrc_in = ei;
  const int* edst_in = ei + N_EDGES;

  const float* w1[3], * b1[3], * w2[3], * b2[3], * gg[3], * bt[3];
  for (int l = 0; l < 3; ++l) {
    w1[l] = (const float*)d_in[3 + 6 * l];
    b1[l] = (const float*)d_in[4 + 6 * l];
    w2[l] = (const float*)d_in[5 + 6 * l];
    b2[l] = (const float*)d_in[6 + 6 * l];
    gg[l] = (const float*)d_in[7 + 6 * l];
    bt[l] = (const float*)d_in[8 + 6 * l];
  }
  const float* fw1 = (const float*)d_in[21];
  const float* fb1 = (const float*)d_in[22];
  const float* fw2 = (const float*)d_in[23];
  const float* fb2 = (const float*)d_in[24];

  char* p = (char*)d_ws;
  float* bufA  = (float*)p;                 p += (size_t)N_NODES * HID * 4;   // 25.6 MB
  float* bufB  = (float*)p;                 p += (size_t)N_NODES * HID * 4;   // 25.6 MB
  int*   esrc  = (int*)p;                   p += (size_t)N_EDGES * 4;         // 6.4 MB
  int*   deg   = (int*)p;                   p += (size_t)N_NODES * 4;
  int*   off   = (int*)p;                   p += 400016;                      // N_NODES+1 ints
  int*   cur   = (int*)p;                   p += (size_t)N_NODES * 4;
  int*   bsum  = (int*)p;                   p += 2048;
  float* stats = (float*)p;                 p += 1024;                        // sums(128) + scale/shift(128)
  float* pooled = (float*)p;                p += (size_t)NUM_GRAPHS * HID * 4;
  int*   gstart = (int*)p;                  p += 1024;                        // 129 ints
  (void)ws_size; (void)in_sizes; (void)n_in; (void)out_size;

  // ---- CSR build (once per call) ----
  hipMemsetAsync(deg, 0, (size_t)N_NODES * 4, stream);
  k_deg<<<2048, 256, 0, stream>>>(edst_in, deg);
  k_scan_block<<<NBLK_SCAN, 256, 0, stream>>>(deg, off, bsum);
  k_scan_tops<<<1, 512, 0, stream>>>(bsum);
  k_scan_add<<<NBLK_SCAN, 256, 0, stream>>>(deg, off, bsum, cur);
  k_fill<<<2048, 256, 0, stream>>>(esrc_in, edst_in, cur, esrc);
  k_bounds<<<1, 192, 0, stream>>>(batch, gstart);

  // ---- 3 GIN layers ----
  const float* Xs[3] = { x, bufA, bufB };
  float*       Os[3] = { bufA, bufB, bufA };
  for (int l = 0; l < 3; ++l) {
    k_gather<<<N_NODES * 64 / 256, 256, 0, stream>>>(Xs[l], off, esrc, Os[l]);
    k_mlp<<<(N_NODES + 255) / 256, 256, 0, stream>>>(Xs[l], Os[l], w1[l], b1[l], w2[l], b2[l], Os[l]);
    hipMemsetAsync(stats, 0, 128 * 4, stream);
    k_stats<<<512, 256, 0, stream>>>(Os[l], stats);
    k_bnparams<<<1, 64, 0, stream>>>(stats, stats + 128, gg[l], bt[l]);
    k_bnrelu<<<N_NODES * 16 / 256, 256, 0, stream>>>(Os[l], stats + 128, Os[l]);
  }

  // ---- pool + head ----
  k_pool2<<<NUM_GRAPHS, 256, 0, stream>>>(Os[2], gstart, pooled);
  k_final<<<NUM_GRAPHS, 64, 0, stream>>>(pooled, fw1, fb1, fw2, fb2, (float*)d_out);
}

// Round 3
// 784.094 us; speedup vs baseline: 1.4221x; 1.0047x over previous
//
#include <hip/hip_runtime.h>

#define N_NODES   100000
#define N_EDGES   1600000
#define HID       64
#define NUM_GRAPHS 128
#define BN_EPS    1e-5f
#define NBLK_SCAN 391   // ceil(N_NODES/256)

#define NXCD        8
#define NODE_RANGE  (N_NODES / NXCD)     // 12500 nodes per XCD-owned range
#define FILL_CHUNKS 128
#define CHUNK_E     (N_EDGES / FILL_CHUNKS) // 12500 edges per chunk
#define STAT_BLKS   128

// ---------------- CSR build (XCD-partitioned: block b -> dst range b&7) ----------------

__global__ void k_deg(const int* __restrict__ dst, int* __restrict__ deg) {
  int r = blockIdx.x & (NXCD - 1);      // XCD-local dst range
  int c = blockIdx.x >> 3;              // edge chunk
  int lo = r * NODE_RANGE, hi = lo + NODE_RANGE;
  int base = c * CHUNK_E;
  for (int i = threadIdx.x; i < CHUNK_E; i += 256) {
    int d = dst[base + i];
    if (d >= lo && d < hi) atomicAdd(&deg[d], 1);
  }
}

__global__ void k_scan_block(const int* __restrict__ deg, int* __restrict__ off,
                             int* __restrict__ bsum) {
  __shared__ int s[256];
  int b = blockIdx.x, t = threadIdx.x;
  int i = b * 256 + t;
  int v = (i < N_NODES) ? deg[i] : 0;
  s[t] = v;
  __syncthreads();
  for (int d = 1; d < 256; d <<= 1) {
    int x = (t >= d) ? s[t - d] : 0;
    __syncthreads();
    s[t] += x;
    __syncthreads();
  }
  if (i < N_NODES) off[i + 1] = s[t];   // block-local inclusive
  if (t == 255) bsum[b] = s[255];
}

__global__ void k_scan_tops(int* __restrict__ bsum) {
  __shared__ int s[512];
  int t = threadIdx.x;
  int v = (t < NBLK_SCAN) ? bsum[t] : 0;
  s[t] = v;
  __syncthreads();
  for (int d = 1; d < 512; d <<= 1) {
    int x = (t >= d) ? s[t - d] : 0;
    __syncthreads();
    s[t] += x;
    __syncthreads();
  }
  if (t < NBLK_SCAN) bsum[t] = s[t] - v;  // exclusive over block sums
}

__global__ void k_scan_add(const int* __restrict__ deg, int* __restrict__ off,
                           const int* __restrict__ bsum, int* __restrict__ cur) {
  int b = blockIdx.x, t = threadIdx.x;
  int i = b * 256 + t;
  if (i >= N_NODES) return;
  int fin = off[i + 1] + bsum[b];
  off[i + 1] = fin;
  cur[i] = fin - deg[i];  // start position of node i's edge slots
  if (i == 0) off[0] = 0;
}

__global__ void k_fill(const int* __restrict__ src, const int* __restrict__ dst,
                       int* __restrict__ cur, int* __restrict__ esrc) {
  int r = blockIdx.x & (NXCD - 1);
  int c = blockIdx.x >> 3;
  int lo = r * NODE_RANGE, hi = lo + NODE_RANGE;
  int base = c * CHUNK_E;
  for (int i = threadIdx.x; i < CHUNK_E; i += 256) {
    int d = dst[base + i];
    if (d >= lo && d < hi) {
      int pos = atomicAdd(&cur[d], 1);
      esrc[pos] = src[base + i];
    }
  }
}

// ---------------- per-layer kernels ----------------

// one wave per node, lane = feature; pull-gather, no atomics.
// BN=true: input rows are raw MLP output of previous layer -> apply relu(v*scale+shift)
// on the fly. Also adds the (BN'd) self row, so AGG = x + sum_neighbors(x).
template<bool BN>
__global__ void k_gather(const float* __restrict__ X, const int* __restrict__ off,
                         const int* __restrict__ esrc, const float* __restrict__ sc,
                         float* __restrict__ agg) {
  int gid = blockIdx.x * blockDim.x + threadIdx.x;
  int w = gid >> 6;
  int t = gid & 63;
  if (w >= N_NODES) return;
  float scale = 1.f, shift = 0.f;
  if (BN) { scale = sc[t]; shift = sc[64 + t]; }
  int s0 = off[w], s1 = off[w + 1];
  float xv = X[w * HID + t];
  float acc = BN ? fmaxf(fmaf(xv, scale, shift), 0.f) : xv;  // self term
  int i = s0;
  for (; i + 4 <= s1; i += 4) {
    int a = esrc[i], b = esrc[i + 1], c = esrc[i + 2], d = esrc[i + 3];
    float va = X[a * HID + t];
    float vb = X[b * HID + t];
    float vc = X[c * HID + t];
    float vd = X[d * HID + t];
    if (BN) {
      va = fmaxf(fmaf(va, scale, shift), 0.f);
      vb = fmaxf(fmaf(vb, scale, shift), 0.f);
      vc = fmaxf(fmaf(vc, scale, shift), 0.f);
      vd = fmaxf(fmaf(vd, scale, shift), 0.f);
    }
    acc += va + vb + vc + vd;
  }
  for (; i < s1; ++i) {
    float v = X[esrc[i] * HID + t];
    if (BN) v = fmaxf(fmaf(v, scale, shift), 0.f);
    acc += v;
  }
  agg[w * HID + t] = acc;
}

// thread-per-node fused 2-layer MLP over AGG rows (in-place OK: own row only)
__global__ __launch_bounds__(256, 2) void k_mlp(
    const float* AGG,
    const float* __restrict__ w1, const float* __restrict__ b1,
    const float* __restrict__ w2, const float* __restrict__ b2,
    float* OUT) {
  int n = blockIdx.x * blockDim.x + threadIdx.x;
  if (n >= N_NODES) return;
  const float* ar = AGG + n * HID;
  float h[HID];
#pragma unroll
  for (int k = 0; k < HID; k += 4) {
    float4 g = *(const float4*)(ar + k);
    h[k] = g.x; h[k + 1] = g.y; h[k + 2] = g.z; h[k + 3] = g.w;
  }
  float hid[HID];
#pragma unroll
  for (int j = 0; j < HID; ++j) hid[j] = b1[j];
#pragma unroll
  for (int k = 0; k < HID; ++k) {
    const float* wr = w1 + k * HID;
#pragma unroll
    for (int j = 0; j < HID; ++j) hid[j] = fmaf(h[k], wr[j], hid[j]);
  }
#pragma unroll
  for (int j = 0; j < HID; ++j) hid[j] = fmaxf(hid[j], 0.f);
  float o[HID];
#pragma unroll
  for (int j = 0; j < HID; ++j) o[j] = b2[j];
#pragma unroll
  for (int k = 0; k < HID; ++k) {
    const float* wr = w2 + k * HID;
#pragma unroll
    for (int j = 0; j < HID; ++j) o[j] = fmaf(hid[k], wr[j], o[j]);
  }
  float* orow = OUT + n * HID;
#pragma unroll
  for (int j = 0; j < HID; j += 4) {
    float4 v; v.x = o[j]; v.y = o[j + 1]; v.z = o[j + 2]; v.w = o[j + 3];
    *(float4*)(orow + j) = v;
  }
}

// column sums / sumsq -> per-block partials (atomic-free)
__global__ void k_stats(const float* __restrict__ H, float* __restrict__ part) {
  int f = threadIdx.x & 63;
  int wv = threadIdx.x >> 6;
  float s = 0.f, q = 0.f;
  int walker = blockIdx.x * 4 + wv;          // 512 walkers
  for (int n = walker; n < N_NODES; n += STAT_BLKS * 4) {
    float v = H[n * HID + f];
    s += v; q += v * v;
  }
  __shared__ float ls[256], lq[256];
  ls[threadIdx.x] = s; lq[threadIdx.x] = q;
  __syncthreads();
  if (threadIdx.x < 64) {
    s = ls[threadIdx.x] + ls[64 + threadIdx.x] + ls[128 + threadIdx.x] + ls[192 + threadIdx.x];
    q = lq[threadIdx.x] + lq[64 + threadIdx.x] + lq[128 + threadIdx.x] + lq[192 + threadIdx.x];
    part[blockIdx.x * 128 + threadIdx.x] = s;
    part[blockIdx.x * 128 + 64 + threadIdx.x] = q;
  }
}

// reduce partials, produce scale/shift; sc[0..63]=scale, sc[64..127]=shift
__global__ void k_bnparams(const float* __restrict__ part, float* __restrict__ sc,
                           const float* __restrict__ gamma, const float* __restrict__ beta) {
  int t = threadIdx.x;  // 128 threads
  float tot = 0.f;
  for (int b = 0; b < STAT_BLKS; ++b) tot += part[b * 128 + t];
  __shared__ float s[128];
  s[t] = tot;
  __syncthreads();
  if (t < 64) {
    float mean = s[t] * (1.0f / N_NODES);
    float var = s[64 + t] * (1.0f / N_NODES) - mean * mean;
    float scale = gamma[t] * rsqrtf(var + BN_EPS);
    sc[t] = scale;
    sc[64 + t] = beta[t] - mean * scale;
  }
}

// ---------------- pooling + head (batch is SORTED -> segment boundaries) ----------------

__global__ void k_bounds(const int* __restrict__ batch, int* __restrict__ gstart) {
  int g = threadIdx.x;
  if (g > NUM_GRAPHS) return;
  int lo = 0, hi = N_NODES;
  while (lo < hi) {
    int mid = (lo + hi) >> 1;
    if (batch[mid] < g) lo = mid + 1; else hi = mid;
  }
  gstart[g] = lo;
}

// one block per graph: BN+ReLU applied inline on raw layer-3 MLP output
__global__ void k_pool2(const float* __restrict__ H, const int* __restrict__ gstart,
                        const float* __restrict__ sc, float* __restrict__ pooled) {
  int g = blockIdx.x;
  int s0 = gstart[g], s1 = gstart[g + 1];
  int wv = threadIdx.x >> 6, lane = threadIdx.x & 63;
  float scale = sc[lane], shift = sc[64 + lane];
  float acc = 0.f;
  for (int n = s0 + wv; n < s1; n += 4)
    acc += fmaxf(fmaf(H[n * HID + lane], scale, shift), 0.f);
  __shared__ float ls[256];
  ls[threadIdx.x] = acc;
  __syncthreads();
  if (threadIdx.x < 64) {
    float v = ls[threadIdx.x] + ls[64 + threadIdx.x] + ls[128 + threadIdx.x] + ls[192 + threadIdx.x];
    float cnt = fmaxf((float)(s1 - s0), 1.0f);
    pooled[g * HID + threadIdx.x] = v / cnt;
  }
}

__global__ void k_final(const float* __restrict__ pooled,
                        const float* __restrict__ fw1, const float* __restrict__ fb1,
                        const float* __restrict__ fw2, const float* __restrict__ fb2,
                        float* __restrict__ out) {
  int g = blockIdx.x, t = threadIdx.x;
  __shared__ float row[64];
  row[t] = pooled[g * HID + t];
  __syncthreads();
  float acc = fb1[t];
  for (int k = 0; k < HID; ++k) acc = fmaf(row[k], fw1[k * HID + t], acc);
  float h = fmaxf(acc, 0.f);
  float v = h * fw2[t];
  for (int o = 32; o > 0; o >>= 1) v += __shfl_down(v, o);
  if (t == 0) out[g] = fmaxf(v + fb2[0], 0.f);
}

// ---------------- launch ----------------

extern "C" void kernel_launch(void* const* d_in, const int* in_sizes, int n_in,
                              void* d_out, int out_size, void* d_ws, size_t ws_size,
                              hipStream_t stream) {
  const float* x     = (const float*)d_in[0];
  const int*   ei    = (const int*)d_in[1];
  const int*   batch = (const int*)d_in[2];
  const int* esrc_in = ei;
  const int* edst_in = ei + N_EDGES;

  const float* w1[3], * b1[3], * w2[3], * b2[3], * gg[3], * bt[3];
  for (int l = 0; l < 3; ++l) {
    w1[l] = (const float*)d_in[3 + 6 * l];
    b1[l] = (const float*)d_in[4 + 6 * l];
    w2[l] = (const float*)d_in[5 + 6 * l];
    b2[l] = (const float*)d_in[6 + 6 * l];
    gg[l] = (const float*)d_in[7 + 6 * l];
    bt[l] = (const float*)d_in[8 + 6 * l];
  }
  const float* fw1 = (const float*)d_in[21];
  const float* fb1 = (const float*)d_in[22];
  const float* fw2 = (const float*)d_in[23];
  const float* fb2 = (const float*)d_in[24];

  char* p = (char*)d_ws;
  float* bufA  = (float*)p;                 p += (size_t)N_NODES * HID * 4;   // 25.6 MB
  float* bufB  = (float*)p;                 p += (size_t)N_NODES * HID * 4;   // 25.6 MB
  int*   esrc  = (int*)p;                   p += (size_t)N_EDGES * 4;         // 6.4 MB
  int*   deg   = (int*)p;                   p += (size_t)N_NODES * 4;
  int*   off   = (int*)p;                   p += 400016;                      // N_NODES+1 ints
  int*   cur   = (int*)p;                   p += (size_t)N_NODES * 4;
  int*   bsum  = (int*)p;                   p += 2048;
  float* part  = (float*)p;                 p += (size_t)STAT_BLKS * 128 * 4; // 64 KB
  float* sc1   = (float*)p;                 p += 512;
  float* sc2   = (float*)p;                 p += 512;
  float* sc3   = (float*)p;                 p += 512;
  float* pooled = (float*)p;                p += (size_t)NUM_GRAPHS * HID * 4;
  int*   gstart = (int*)p;                  p += 1024;                        // 129 ints
  (void)ws_size; (void)in_sizes; (void)n_in; (void)out_size;

  // ---- CSR build (once per call) ----
  hipMemsetAsync(deg, 0, (size_t)N_NODES * 4, stream);
  k_deg<<<NXCD * FILL_CHUNKS, 256, 0, stream>>>(edst_in, deg);
  k_scan_block<<<NBLK_SCAN, 256, 0, stream>>>(deg, off, bsum);
  k_scan_tops<<<1, 512, 0, stream>>>(bsum);
  k_scan_add<<<NBLK_SCAN, 256, 0, stream>>>(deg, off, bsum, cur);
  k_fill<<<NXCD * FILL_CHUNKS, 256, 0, stream>>>(esrc_in, edst_in, cur, esrc);
  k_bounds<<<1, 192, 0, stream>>>(batch, gstart);

  // ---- 3 GIN layers (bnrelu fused into next gather / pooling) ----
  // L1: gather(x) -> A ; mlp A->A ; stats(A) -> sc1
  k_gather<false><<<N_NODES * 64 / 256, 256, 0, stream>>>(x, off, esrc, nullptr, bufA);
  k_mlp<<<(N_NODES + 255) / 256, 256, 0, stream>>>(bufA, w1[0], b1[0], w2[0], b2[0], bufA);
  k_stats<<<STAT_BLKS, 256, 0, stream>>>(bufA, part);
  k_bnparams<<<1, 128, 0, stream>>>(part, sc1, gg[0], bt[0]);
  // L2: gather(bn(A)) -> B ; mlp B->B ; stats(B) -> sc2
  k_gather<true><<<N_NODES * 64 / 256, 256, 0, stream>>>(bufA, off, esrc, sc1, bufB);
  k_mlp<<<(N_NODES + 255) / 256, 256, 0, stream>>>(bufB, w1[1], b1[1], w2[1], b2[1], bufB);
  k_stats<<<STAT_BLKS, 256, 0, stream>>>(bufB, part);
  k_bnparams<<<1, 128, 0, stream>>>(part, sc2, gg[1], bt[1]);
  // L3: gather(bn(B)) -> A ; mlp A->A ; stats(A) -> sc3
  k_gather<true><<<N_NODES * 64 / 256, 256, 0, stream>>>(bufB, off, esrc, sc2, bufA);
  k_mlp<<<(N_NODES + 255) / 256, 256, 0, stream>>>(bufA, w1[2], b1[2], w2[2], b2[2], bufA);
  k_stats<<<STAT_BLKS, 256, 0, stream>>>(bufA, part);
  k_bnparams<<<1, 128, 0, stream>>>(part, sc3, gg[2], bt[2]);

  // ---- pool (BN fused) + head ----
  k_pool2<<<NUM_GRAPHS, 256, 0, stream>>>(bufA, gstart, sc3, pooled);
  k_final<<<NUM_GRAPHS, 64, 0, stream>>>(pooled, fw1, fb1, fw2, fb2, (float*)d_out);
}

// Round 4
// 755.413 us; speedup vs baseline: 1.4761x; 1.0380x over previous
//
#include <hip/hip_runtime.h>

#define N_NODES    100000
#define N_EDGES    1600000
#define HID        64
#define NUM_GRAPHS 128
#define BN_EPS     1e-5f
#define NBLK_SCAN  391            // ceil(N_NODES/256)

#define NXCD       8
#define NODE_RANGE (N_NODES / NXCD)   // 12500 nodes per bucket
#define PBLKS      512                // partition blocks
#define EPB        (N_EDGES / PBLKS)  // 3125 edges per partition block

#define MLP_BLKS   782                // ceil(100000/128)
#define NPARTS     (MLP_BLKS * 2)     // one partial per wave
#define LSTRIDE    65                 // padded LDS row stride (floats)

// ================= CSR build: radix partition + XCD-local fill =================

// P1a: per-block bucket histogram (wave-ballot aggregated)
__global__ void k_pcount(const int* __restrict__ dst, int* __restrict__ blockHist) {
  __shared__ int h[8];
  if (threadIdx.x < 8) h[threadIdx.x] = 0;
  __syncthreads();
  int lane = threadIdx.x & 63;
  int seg0 = blockIdx.x * EPB;
  int mycnt = 0;
  for (int i = threadIdx.x; i < EPB; i += 256) {
    int b = dst[seg0 + i] / NODE_RANGE;
#pragma unroll
    for (int bb = 0; bb < 8; ++bb) {
      int c = __popcll(__ballot(b == bb));
      if (lane == bb) mycnt += c;
    }
  }
  if (lane < 8) atomicAdd(&h[lane], mycnt);
  __syncthreads();
  if (threadIdx.x < 8) blockHist[blockIdx.x * 8 + threadIdx.x] = h[threadIdx.x];
}

// P1b: exclusive scan of per-block counts within each bucket + bucket bases
__global__ void k_p1scan(const int* __restrict__ blockHist, int* __restrict__ blockBase,
                         int* __restrict__ bucketStart) {
  __shared__ int s[PBLKS];
  __shared__ int tot[8];
  int t = threadIdx.x;
  for (int b = 0; b < 8; ++b) {
    int v = blockHist[t * 8 + b];
    s[t] = v; __syncthreads();
    for (int d = 1; d < PBLKS; d <<= 1) {
      int x = (t >= d) ? s[t - d] : 0; __syncthreads();
      s[t] += x; __syncthreads();
    }
    blockBase[t * 8 + b] = s[t] - v;
    if (t == PBLKS - 1) tot[b] = s[t];
    __syncthreads();
  }
  if (t == 0) {
    int acc = 0;
    for (int b = 0; b < 8; ++b) { bucketStart[b] = acc; acc += tot[b]; }
    bucketStart[8] = acc;
  }
}

// P1c: write compacted (src,dst) pairs into bucket regions (coalesced, no global atomics)
__global__ void k_part(const int* __restrict__ src, const int* __restrict__ dst,
                       const int* __restrict__ blockBase, const int* __restrict__ bucketStart,
                       int2* __restrict__ bout) {
  __shared__ int lcur[8];
  if (threadIdx.x < 8)
    lcur[threadIdx.x] = bucketStart[threadIdx.x] + blockBase[blockIdx.x * 8 + threadIdx.x];
  __syncthreads();
  int lane = threadIdx.x & 63;
  int seg0 = blockIdx.x * EPB;
  for (int i = threadIdx.x; i < EPB; i += 256) {
    int d = dst[seg0 + i], sv = src[seg0 + i];
    int b = d / NODE_RANGE;
#pragma unroll
    for (int bb = 0; bb < 8; ++bb) {
      unsigned long long m = __ballot(b == bb);
      if (b == bb) {
        int rank = __popcll(m & ((1ull << lane) - 1ull));
        int leader = __ffsll((unsigned long long)m) - 1;
        int base = 0;
        if (lane == leader) base = atomicAdd(&lcur[bb], __popcll(m));
        base = __shfl(base, leader);
        bout[base + rank] = make_int2(sv, d);
      }
    }
  }
}

// P2a: degree count, XCD-pinned per bucket (persistent grid 2048 = 8 blocks/CU)
__global__ void k_deg2(const int2* __restrict__ bout, const int* __restrict__ bucketStart,
                       int* __restrict__ deg) {
  int r = blockIdx.x & 7, c = blockIdx.x >> 3;
  int lo = bucketStart[r], hi = bucketStart[r + 1];
  int sz = (hi - lo + 255) >> 8;
  int s0 = lo + c * sz, s1 = min(s0 + sz, hi);
  for (int i = s0 + threadIdx.x; i < s1; i += 256) atomicAdd(&deg[bout[i].y], 1);
}

__global__ void k_scan_block(const int* __restrict__ deg, int* __restrict__ off,
                             int* __restrict__ bsum) {
  __shared__ int s[256];
  int b = blockIdx.x, t = threadIdx.x;
  int i = b * 256 + t;
  int v = (i < N_NODES) ? deg[i] : 0;
  s[t] = v;
  __syncthreads();
  for (int d = 1; d < 256; d <<= 1) {
    int x = (t >= d) ? s[t - d] : 0;
    __syncthreads();
    s[t] += x;
    __syncthreads();
  }
  if (i < N_NODES) off[i + 1] = s[t];
  if (t == 255) bsum[b] = s[255];
}

__global__ void k_scan_tops(int* __restrict__ bsum) {
  __shared__ int s[512];
  int t = threadIdx.x;
  int v = (t < NBLK_SCAN) ? bsum[t] : 0;
  s[t] = v;
  __syncthreads();
  for (int d = 1; d < 512; d <<= 1) {
    int x = (t >= d) ? s[t - d] : 0;
    __syncthreads();
    s[t] += x;
    __syncthreads();
  }
  if (t < NBLK_SCAN) bsum[t] = s[t] - v;
}

__global__ void k_scan_add(const int* __restrict__ deg, int* __restrict__ off,
                           const int* __restrict__ bsum, int* __restrict__ cur) {
  int b = blockIdx.x, t = threadIdx.x;
  int i = b * 256 + t;
  if (i >= N_NODES) return;
  int fin = off[i + 1] + bsum[b];
  off[i + 1] = fin;
  cur[i] = fin - deg[i];
  if (i == 0) off[0] = 0;
}

// P2b: fill esrc, XCD-pinned per bucket (cur slice ~50KB, esrc slice ~800KB stay in L2)
__global__ void k_fill2(const int2* __restrict__ bout, const int* __restrict__ bucketStart,
                        int* __restrict__ cur, int* __restrict__ esrc) {
  int r = blockIdx.x & 7, c = blockIdx.x >> 3;
  int lo = bucketStart[r], hi = bucketStart[r + 1];
  int sz = (hi - lo + 255) >> 8;
  int s0 = lo + c * sz, s1 = min(s0 + sz, hi);
  for (int i = s0 + threadIdx.x; i < s1; i += 256) {
    int2 e = bout[i];
    int pos = atomicAdd(&cur[e.y], 1);
    esrc[pos] = e.x;
  }
}

// ================= per-layer kernels =================

// one wave per node, lane = feature; pull-gather; BN of PREVIOUS layer fused on the fly
template<bool BN>
__global__ void k_gather(const float* __restrict__ X, const int* __restrict__ off,
                         const int* __restrict__ esrc, const float* __restrict__ sc,
                         float* __restrict__ agg) {
  int gid = blockIdx.x * blockDim.x + threadIdx.x;
  int w = gid >> 6;
  int t = gid & 63;
  if (w >= N_NODES) return;
  float scale = 1.f, shift = 0.f;
  if (BN) { scale = sc[t]; shift = sc[64 + t]; }
  int s0 = off[w], s1 = off[w + 1];
  float xv = X[w * HID + t];
  float acc = BN ? fmaxf(fmaf(xv, scale, shift), 0.f) : xv;  // self term
  int i = s0;
  for (; i + 4 <= s1; i += 4) {
    int a = esrc[i], b = esrc[i + 1], c = esrc[i + 2], d = esrc[i + 3];
    float va = X[a * HID + t];
    float vb = X[b * HID + t];
    float vc = X[c * HID + t];
    float vd = X[d * HID + t];
    if (BN) {
      va = fmaxf(fmaf(va, scale, shift), 0.f);
      vb = fmaxf(fmaf(vb, scale, shift), 0.f);
      vc = fmaxf(fmaf(vc, scale, shift), 0.f);
      vd = fmaxf(fmaf(vd, scale, shift), 0.f);
    }
    acc += va + vb + vc + vd;
  }
  for (; i < s1; ++i) {
    float v = X[esrc[i] * HID + t];
    if (BN) v = fmaxf(fmaf(v, scale, shift), 0.f);
    acc += v;
  }
  agg[w * HID + t] = acc;
}

// Fused 2-layer MLP: per-thread row lives in LDS (runtime-indexable, conflict-free),
// accumulators static-indexed in VGPRs. BN column-stat partials fused in epilogue.
__global__ __launch_bounds__(128, 2) void k_mlp(
    const float* __restrict__ AGG,
    const float* __restrict__ w1, const float* __restrict__ b1,
    const float* __restrict__ w2, const float* __restrict__ b2,
    float* __restrict__ OUT, float* __restrict__ part) {
  __shared__ float panel[2][64 * LSTRIDE];
  int wv = threadIdx.x >> 6, lane = threadIdx.x & 63;
  float* P = panel[wv];
  int waveIdx = blockIdx.x * 2 + wv;
  int nodeBase = waveIdx * 64;

  // stage 64 rows, coalesced float4
  {
    int rsub = lane >> 4, c4 = lane & 15;
    for (int r0 = 0; r0 < 64; r0 += 4) {
      int row = r0 + rsub;
      int g = nodeBase + row; if (g > N_NODES - 1) g = N_NODES - 1;
      float4 v = *(const float4*)(AGG + (size_t)g * HID + c4 * 4);
      *(float4*)(P + row * LSTRIDE + c4 * 4) = v;
    }
  }
  __syncthreads();

  float* myrow = P + lane * LSTRIDE;
  float acc[HID];
#pragma unroll
  for (int j = 0; j < HID; ++j) acc[j] = b1[j];
  for (int k = 0; k < HID; ++k) {           // k runtime: only the LDS read uses it
    float xv = myrow[k];
    const float* wr = w1 + k * HID;         // uniform -> scalar loads
#pragma unroll
    for (int j = 0; j < HID; ++j) acc[j] = fmaf(xv, wr[j], acc[j]);
  }
#pragma unroll
  for (int j = 0; j < HID; ++j) myrow[j] = fmaxf(acc[j], 0.f);   // hid -> own LDS row
#pragma unroll
  for (int j = 0; j < HID; ++j) acc[j] = b2[j];
  for (int k = 0; k < HID; ++k) {
    float hv = myrow[k];
    const float* wr = w2 + k * HID;
#pragma unroll
    for (int j = 0; j < HID; ++j) acc[j] = fmaf(hv, wr[j], acc[j]);
  }
#pragma unroll
  for (int j = 0; j < HID; ++j) myrow[j] = acc[j];               // raw out -> own LDS row
  __syncthreads();

  // coalesced store
  {
    int rsub = lane >> 4, c4 = lane & 15;
    for (int r0 = 0; r0 < 64; r0 += 4) {
      int row = r0 + rsub;
      int g = nodeBase + row;
      if (g < N_NODES) {
        float4 v = *(const float4*)(P + row * LSTRIDE + c4 * 4);
        *(float4*)(OUT + (size_t)g * HID + c4 * 4) = v;
      }
    }
  }
  // fused BN stats: per-wave column partial sums over valid rows
  int vcnt = N_NODES - nodeBase;
  if (vcnt > 64) vcnt = 64;
  if (vcnt < 0) vcnt = 0;
  float s = 0.f, q = 0.f;
  for (int r = 0; r < vcnt; ++r) {
    float v = P[r * LSTRIDE + lane];
    s += v; q += v * v;
  }
  part[waveIdx * 128 + lane] = s;
  part[waveIdx * 128 + 64 + lane] = q;
}

// reduce wave partials -> BN scale/shift
__global__ void k_bnparams(const float* __restrict__ part, float* __restrict__ sc,
                           const float* __restrict__ gamma, const float* __restrict__ beta) {
  __shared__ float red[8][128];
  int t = threadIdx.x;          // 1024 threads
  int col = t & 127, grp = t >> 7;
  float acc = 0.f;
  for (int b = grp; b < NPARTS; b += 8) acc += part[b * 128 + col];
  red[grp][col] = acc;
  __syncthreads();
  if (t < 128) {
    float tot = red[0][t] + red[1][t] + red[2][t] + red[3][t]
              + red[4][t] + red[5][t] + red[6][t] + red[7][t];
    red[0][t] = tot;
  }
  __syncthreads();
  if (t < 64) {
    float mean = red[0][t] * (1.0f / N_NODES);
    float var  = red[0][64 + t] * (1.0f / N_NODES) - mean * mean;
    float scale = gamma[t] * rsqrtf(var + BN_EPS);
    sc[t] = scale;
    sc[64 + t] = beta[t] - mean * scale;
  }
}

// ================= pooling + head (batch sorted -> segments) =================

__global__ void k_bounds(const int* __restrict__ batch, int* __restrict__ gstart) {
  int g = threadIdx.x;
  if (g > NUM_GRAPHS) return;
  int lo = 0, hi = N_NODES;
  while (lo < hi) {
    int mid = (lo + hi) >> 1;
    if (batch[mid] < g) lo = mid + 1; else hi = mid;
  }
  gstart[g] = lo;
}

__global__ void k_pool2(const float* __restrict__ H, const int* __restrict__ gstart,
                        const float* __restrict__ sc, float* __restrict__ pooled) {
  int g = blockIdx.x;
  int s0 = gstart[g], s1 = gstart[g + 1];
  int wv = threadIdx.x >> 6, lane = threadIdx.x & 63;
  float scale = sc[lane], shift = sc[64 + lane];
  float acc = 0.f;
  for (int n = s0 + wv; n < s1; n += 4)
    acc += fmaxf(fmaf(H[n * HID + lane], scale, shift), 0.f);
  __shared__ float ls[256];
  ls[threadIdx.x] = acc;
  __syncthreads();
  if (threadIdx.x < 64) {
    float v = ls[threadIdx.x] + ls[64 + threadIdx.x] + ls[128 + threadIdx.x] + ls[192 + threadIdx.x];
    float cnt = fmaxf((float)(s1 - s0), 1.0f);
    pooled[g * HID + threadIdx.x] = v / cnt;
  }
}

__global__ void k_final(const float* __restrict__ pooled,
                        const float* __restrict__ fw1, const float* __restrict__ fb1,
                        const float* __restrict__ fw2, const float* __restrict__ fb2,
                        float* __restrict__ out) {
  int g = blockIdx.x, t = threadIdx.x;
  __shared__ float row[64];
  row[t] = pooled[g * HID + t];
  __syncthreads();
  float acc = fb1[t];
  for (int k = 0; k < HID; ++k) acc = fmaf(row[k], fw1[k * HID + t], acc);
  float h = fmaxf(acc, 0.f);
  float v = h * fw2[t];
  for (int o = 32; o > 0; o >>= 1) v += __shfl_down(v, o);
  if (t == 0) out[g] = fmaxf(v + fb2[0], 0.f);
}

// ================= launch =================

extern "C" void kernel_launch(void* const* d_in, const int* in_sizes, int n_in,
                              void* d_out, int out_size, void* d_ws, size_t ws_size,
                              hipStream_t stream) {
  const float* x     = (const float*)d_in[0];
  const int*   ei    = (const int*)d_in[1];
  const int*   batch = (const int*)d_in[2];
  const int* esrc_in = ei;
  const int* edst_in = ei + N_EDGES;

  const float* w1[3], * b1[3], * w2[3], * b2[3], * gg[3], * bt[3];
  for (int l = 0; l < 3; ++l) {
    w1[l] = (const float*)d_in[3 + 6 * l];
    b1[l] = (const float*)d_in[4 + 6 * l];
    w2[l] = (const float*)d_in[5 + 6 * l];
    b2[l] = (const float*)d_in[6 + 6 * l];
    gg[l] = (const float*)d_in[7 + 6 * l];
    bt[l] = (const float*)d_in[8 + 6 * l];
  }
  const float* fw1 = (const float*)d_in[21];
  const float* fb1 = (const float*)d_in[22];
  const float* fw2 = (const float*)d_in[23];
  const float* fb2 = (const float*)d_in[24];

  char* p = (char*)d_ws;
  float* bufA   = (float*)p;   p += (size_t)N_NODES * HID * 4;   // 25.6 MB
  float* bufB   = (float*)p;   p += (size_t)N_NODES * HID * 4;   // 25.6 MB
  int2*  bout   = (int2*)bufB;                                   // overlay: dead before L2 gather
  int*   esrc   = (int*)p;     p += (size_t)N_EDGES * 4;         // 6.4 MB
  int*   deg    = (int*)p;     p += (size_t)N_NODES * 4;
  int*   off    = (int*)p;     p += 400016;
  int*   cur    = (int*)p;     p += (size_t)N_NODES * 4;
  int*   bsum   = (int*)p;     p += 2048;
  float* part   = (float*)p;   p += (size_t)NPARTS * 128 * 4;    // ~800 KB
  int*   blockHist = (int*)p;  p += PBLKS * 8 * 4;               // 16 KB
  int*   blockBase = (int*)p;  p += PBLKS * 8 * 4;               // 16 KB
  int*   bucketStart = (int*)p; p += 64;
  float* sc1    = (float*)p;   p += 512;
  float* sc2    = (float*)p;   p += 512;
  float* sc3    = (float*)p;   p += 512;
  float* pooled = (float*)p;   p += (size_t)NUM_GRAPHS * HID * 4;
  int*   gstart = (int*)p;     p += 1024;
  (void)ws_size; (void)in_sizes; (void)n_in; (void)out_size;

  // ---- CSR build ----
  k_pcount<<<PBLKS, 256, 0, stream>>>(edst_in, blockHist);
  k_p1scan<<<1, PBLKS, 0, stream>>>(blockHist, blockBase, bucketStart);
  k_part<<<PBLKS, 256, 0, stream>>>(esrc_in, edst_in, blockBase, bucketStart, bout);
  hipMemsetAsync(deg, 0, (size_t)N_NODES * 4, stream);
  k_deg2<<<2048, 256, 0, stream>>>(bout, bucketStart, deg);
  k_scan_block<<<NBLK_SCAN, 256, 0, stream>>>(deg, off, bsum);
  k_scan_tops<<<1, 512, 0, stream>>>(bsum);
  k_scan_add<<<NBLK_SCAN, 256, 0, stream>>>(deg, off, bsum, cur);
  k_fill2<<<2048, 256, 0, stream>>>(bout, bucketStart, cur, esrc);
  k_bounds<<<1, 192, 0, stream>>>(batch, gstart);

  // ---- 3 GIN layers (BN fused into next gather / pooling; stats fused into MLP) ----
  k_gather<false><<<N_NODES * 64 / 256, 256, 0, stream>>>(x, off, esrc, nullptr, bufA);
  k_mlp<<<MLP_BLKS, 128, 0, stream>>>(bufA, w1[0], b1[0], w2[0], b2[0], bufA, part);
  k_bnparams<<<1, 1024, 0, stream>>>(part, sc1, gg[0], bt[0]);

  k_gather<true><<<N_NODES * 64 / 256, 256, 0, stream>>>(bufA, off, esrc, sc1, bufB);
  k_mlp<<<MLP_BLKS, 128, 0, stream>>>(bufB, w1[1], b1[1], w2[1], b2[1], bufB, part);
  k_bnparams<<<1, 1024, 0, stream>>>(part, sc2, gg[1], bt[1]);

  k_gather<true><<<N_NODES * 64 / 256, 256, 0, stream>>>(bufB, off, esrc, sc2, bufA);
  k_mlp<<<MLP_BLKS, 128, 0, stream>>>(bufA, w1[2], b1[2], w2[2], b2[2], bufA, part);
  k_bnparams<<<1, 1024, 0, stream>>>(part, sc3, gg[2], bt[2]);

  // ---- pool (BN fused) + head ----
  k_pool2<<<NUM_GRAPHS, 256, 0, stream>>>(bufA, gstart, sc3, pooled);
  k_final<<<NUM_GRAPHS, 64, 0, stream>>>(pooled, fw1, fb1, fw2, fb2, (float*)d_out);
}

// Round 5
// 699.642 us; speedup vs baseline: 1.5938x; 1.0797x over previous
//
#include <hip/hip_runtime.h>

typedef unsigned short u16;
typedef unsigned int   u32;

#define N_NODES    100000
#define N_EDGES    1600000
#define HID        64
#define NUM_GRAPHS 128
#define BN_EPS     1e-5f
#define NBLK_SCAN  391            // ceil(N_NODES/256)

#define NXCD       8
#define NODE_RANGE (N_NODES / NXCD)   // 12500 nodes per bucket
#define PBLKS      512                // partition blocks
#define EPB        (N_EDGES / PBLKS)  // 3125 edges per partition block

#define MLP_BLKS   782                // ceil(100000/128)
#define NPARTS     (MLP_BLKS * 2)     // one partial per wave
#define LSTRIDE    65                 // padded LDS row stride (floats)

__device__ __forceinline__ float bf2f(u16 u) { return __uint_as_float(((u32)u) << 16); }
__device__ __forceinline__ u16 f2bf(float f) {           // RNE, no NaN handling needed
  u32 u = __float_as_uint(f);
  u32 r = ((u >> 16) & 1u) + 0x7FFFu;
  return (u16)((u + r) >> 16);
}

// ================= CSR build: radix partition + XCD-local fill =================

__global__ void k_pcount(const int* __restrict__ dst, int* __restrict__ blockHist) {
  __shared__ int h[8];
  if (threadIdx.x < 8) h[threadIdx.x] = 0;
  __syncthreads();
  int lane = threadIdx.x & 63;
  int seg0 = blockIdx.x * EPB;
  int mycnt = 0;
  for (int i = threadIdx.x; i < EPB; i += 256) {
    int b = dst[seg0 + i] / NODE_RANGE;
#pragma unroll
    for (int bb = 0; bb < 8; ++bb) {
      int c = __popcll(__ballot(b == bb));
      if (lane == bb) mycnt += c;
    }
  }
  if (lane < 8) atomicAdd(&h[lane], mycnt);
  __syncthreads();
  if (threadIdx.x < 8) blockHist[blockIdx.x * 8 + threadIdx.x] = h[threadIdx.x];
}

__global__ void k_p1scan(const int* __restrict__ blockHist, int* __restrict__ blockBase,
                         int* __restrict__ bucketStart) {
  __shared__ int s[PBLKS];
  __shared__ int tot[8];
  int t = threadIdx.x;
  for (int b = 0; b < 8; ++b) {
    int v = blockHist[t * 8 + b];
    s[t] = v; __syncthreads();
    for (int d = 1; d < PBLKS; d <<= 1) {
      int x = (t >= d) ? s[t - d] : 0; __syncthreads();
      s[t] += x; __syncthreads();
    }
    blockBase[t * 8 + b] = s[t] - v;
    if (t == PBLKS - 1) tot[b] = s[t];
    __syncthreads();
  }
  if (t == 0) {
    int acc = 0;
    for (int b = 0; b < 8; ++b) { bucketStart[b] = acc; acc += tot[b]; }
    bucketStart[8] = acc;
  }
}

__global__ void k_part(const int* __restrict__ src, const int* __restrict__ dst,
                       const int* __restrict__ blockBase, const int* __restrict__ bucketStart,
                       int2* __restrict__ bout) {
  __shared__ int lcur[8];
  if (threadIdx.x < 8)
    lcur[threadIdx.x] = bucketStart[threadIdx.x] + blockBase[blockIdx.x * 8 + threadIdx.x];
  __syncthreads();
  int lane = threadIdx.x & 63;
  int seg0 = blockIdx.x * EPB;
  for (int i = threadIdx.x; i < EPB; i += 256) {
    int d = dst[seg0 + i], sv = src[seg0 + i];
    int b = d / NODE_RANGE;
#pragma unroll
    for (int bb = 0; bb < 8; ++bb) {
      unsigned long long m = __ballot(b == bb);
      if (b == bb) {
        int rank = __popcll(m & ((1ull << lane) - 1ull));
        int leader = __ffsll((unsigned long long)m) - 1;
        int base = 0;
        if (lane == leader) base = atomicAdd(&lcur[bb], __popcll(m));
        base = __shfl(base, leader);
        bout[base + rank] = make_int2(sv, d);
      }
    }
  }
}

__global__ void k_deg2(const int2* __restrict__ bout, const int* __restrict__ bucketStart,
                       int* __restrict__ deg) {
  int r = blockIdx.x & 7, c = blockIdx.x >> 3;
  int lo = bucketStart[r], hi = bucketStart[r + 1];
  int sz = (hi - lo + 255) >> 8;
  int s0 = lo + c * sz, s1 = min(s0 + sz, hi);
  for (int i = s0 + threadIdx.x; i < s1; i += 256) atomicAdd(&deg[bout[i].y], 1);
}

__global__ void k_scan_block(const int* __restrict__ deg, int* __restrict__ off,
                             int* __restrict__ bsum) {
  __shared__ int s[256];
  int b = blockIdx.x, t = threadIdx.x;
  int i = b * 256 + t;
  int v = (i < N_NODES) ? deg[i] : 0;
  s[t] = v;
  __syncthreads();
  for (int d = 1; d < 256; d <<= 1) {
    int x = (t >= d) ? s[t - d] : 0;
    __syncthreads();
    s[t] += x;
    __syncthreads();
  }
  if (i < N_NODES) off[i + 1] = s[t];
  if (t == 255) bsum[b] = s[255];
}

__global__ void k_scan_tops(int* __restrict__ bsum) {
  __shared__ int s[512];
  int t = threadIdx.x;
  int v = (t < NBLK_SCAN) ? bsum[t] : 0;
  s[t] = v;
  __syncthreads();
  for (int d = 1; d < 512; d <<= 1) {
    int x = (t >= d) ? s[t - d] : 0;
    __syncthreads();
    s[t] += x;
    __syncthreads();
  }
  if (t < NBLK_SCAN) bsum[t] = s[t] - v;
}

__global__ void k_scan_add(const int* __restrict__ deg, int* __restrict__ off,
                           const int* __restrict__ bsum, int* __restrict__ cur) {
  int b = blockIdx.x, t = threadIdx.x;
  int i = b * 256 + t;
  if (i >= N_NODES) return;
  int fin = off[i + 1] + bsum[b];
  off[i + 1] = fin;
  cur[i] = fin - deg[i];
  if (i == 0) off[0] = 0;
}

__global__ void k_fill2(const int2* __restrict__ bout, const int* __restrict__ bucketStart,
                        int* __restrict__ cur, int* __restrict__ esrc) {
  int r = blockIdx.x & 7, c = blockIdx.x >> 3;
  int lo = bucketStart[r], hi = bucketStart[r + 1];
  int sz = (hi - lo + 255) >> 8;
  int s0 = lo + c * sz, s1 = min(s0 + sz, hi);
  for (int i = s0 + threadIdx.x; i < s1; i += 256) {
    int2 e = bout[i];
    int pos = atomicAdd(&cur[e.y], 1);
    esrc[pos] = e.x;
  }
}

// ================= misc =================

// fp32 x -> bf16 (once per call)
__global__ void k_tobf16(const float* __restrict__ in, u16* __restrict__ out) {
  int i = blockIdx.x * blockDim.x + threadIdx.x;       // exact grid: N_NODES*16 chunks
  float4 v = ((const float4*)in)[i];
  ushort4 o;
  o.x = f2bf(v.x); o.y = f2bf(v.y); o.z = f2bf(v.z); o.w = f2bf(v.w);
  ((ushort4*)out)[i] = o;
}

// ================= per-layer kernels =================

// one wave per node, lane = feature; pull-gather over bf16 rows, fp32 accumulate.
// BN=true: apply relu(v*scale+shift) (prev layer's BN) to every row on the fly.
template<bool BN>
__global__ void k_gather(const u16* __restrict__ Xb, const int* __restrict__ off,
                         const int* __restrict__ esrc, const float* __restrict__ sc,
                         u16* __restrict__ aggB) {
  int gid = blockIdx.x * blockDim.x + threadIdx.x;
  int w = gid >> 6;
  int t = gid & 63;
  if (w >= N_NODES) return;
  float scale = 1.f, shift = 0.f;
  if (BN) { scale = sc[t]; shift = sc[64 + t]; }
  int s0 = off[w], s1 = off[w + 1];
  float self = bf2f(Xb[(size_t)w * HID + t]);
  float acc = BN ? fmaxf(fmaf(self, scale, shift), 0.f) : self;
  int i = s0;
  for (; i + 8 <= s1; i += 8) {
    int n0 = esrc[i + 0], n1 = esrc[i + 1], n2 = esrc[i + 2], n3 = esrc[i + 3];
    int n4 = esrc[i + 4], n5 = esrc[i + 5], n6 = esrc[i + 6], n7 = esrc[i + 7];
    float v0 = bf2f(Xb[(size_t)n0 * HID + t]);
    float v1 = bf2f(Xb[(size_t)n1 * HID + t]);
    float v2 = bf2f(Xb[(size_t)n2 * HID + t]);
    float v3 = bf2f(Xb[(size_t)n3 * HID + t]);
    float v4 = bf2f(Xb[(size_t)n4 * HID + t]);
    float v5 = bf2f(Xb[(size_t)n5 * HID + t]);
    float v6 = bf2f(Xb[(size_t)n6 * HID + t]);
    float v7 = bf2f(Xb[(size_t)n7 * HID + t]);
    if (BN) {
      v0 = fmaxf(fmaf(v0, scale, shift), 0.f);
      v1 = fmaxf(fmaf(v1, scale, shift), 0.f);
      v2 = fmaxf(fmaf(v2, scale, shift), 0.f);
      v3 = fmaxf(fmaf(v3, scale, shift), 0.f);
      v4 = fmaxf(fmaf(v4, scale, shift), 0.f);
      v5 = fmaxf(fmaf(v5, scale, shift), 0.f);
      v6 = fmaxf(fmaf(v6, scale, shift), 0.f);
      v7 = fmaxf(fmaf(v7, scale, shift), 0.f);
    }
    acc += ((v0 + v1) + (v2 + v3)) + ((v4 + v5) + (v6 + v7));
  }
  for (; i + 4 <= s1; i += 4) {
    int n0 = esrc[i + 0], n1 = esrc[i + 1], n2 = esrc[i + 2], n3 = esrc[i + 3];
    float v0 = bf2f(Xb[(size_t)n0 * HID + t]);
    float v1 = bf2f(Xb[(size_t)n1 * HID + t]);
    float v2 = bf2f(Xb[(size_t)n2 * HID + t]);
    float v3 = bf2f(Xb[(size_t)n3 * HID + t]);
    if (BN) {
      v0 = fmaxf(fmaf(v0, scale, shift), 0.f);
      v1 = fmaxf(fmaf(v1, scale, shift), 0.f);
      v2 = fmaxf(fmaf(v2, scale, shift), 0.f);
      v3 = fmaxf(fmaf(v3, scale, shift), 0.f);
    }
    acc += (v0 + v1) + (v2 + v3);
  }
  for (; i < s1; ++i) {
    float v = bf2f(Xb[(size_t)esrc[i] * HID + t]);
    if (BN) v = fmaxf(fmaf(v, scale, shift), 0.f);
    acc += v;
  }
  aggB[(size_t)w * HID + t] = f2bf(acc);
}

// Fused 2-layer MLP: stage bf16 agg -> fp32 LDS panel; accumulators static in VGPRs;
// outputs written as bf16 shadow only; fp32 BN column-stat partials fused in epilogue.
__global__ __launch_bounds__(128, 2) void k_mlp(
    const u16* __restrict__ AGGB,
    const float* __restrict__ w1, const float* __restrict__ b1,
    const float* __restrict__ w2, const float* __restrict__ b2,
    u16* __restrict__ OUTB, float* __restrict__ part) {
  __shared__ float panel[2][64 * LSTRIDE];
  int wv = threadIdx.x >> 6, lane = threadIdx.x & 63;
  float* P = panel[wv];
  int waveIdx = blockIdx.x * 2 + wv;
  int nodeBase = waveIdx * 64;

  // stage 64 rows: bf16 ushort4 -> float4, coalesced
  {
    int rsub = lane >> 4, c4 = lane & 15;
    for (int r0 = 0; r0 < 64; r0 += 4) {
      int row = r0 + rsub;
      int g = nodeBase + row; if (g > N_NODES - 1) g = N_NODES - 1;
      ushort4 v = *(const ushort4*)(AGGB + (size_t)g * HID + c4 * 4);
      float4 f; f.x = bf2f(v.x); f.y = bf2f(v.y); f.z = bf2f(v.z); f.w = bf2f(v.w);
      *(float4*)(P + row * LSTRIDE + c4 * 4) = f;
    }
  }
  __syncthreads();

  float* myrow = P + lane * LSTRIDE;
  float acc[HID];
#pragma unroll
  for (int j = 0; j < HID; ++j) acc[j] = b1[j];
  for (int k = 0; k < HID; ++k) {           // k runtime: only the LDS read uses it
    float xv = myrow[k];
    const float* wr = w1 + k * HID;         // uniform -> scalar loads
#pragma unroll
    for (int j = 0; j < HID; ++j) acc[j] = fmaf(xv, wr[j], acc[j]);
  }
#pragma unroll
  for (int j = 0; j < HID; ++j) myrow[j] = fmaxf(acc[j], 0.f);
#pragma unroll
  for (int j = 0; j < HID; ++j) acc[j] = b2[j];
  for (int k = 0; k < HID; ++k) {
    float hv = myrow[k];
    const float* wr = w2 + k * HID;
#pragma unroll
    for (int j = 0; j < HID; ++j) acc[j] = fmaf(hv, wr[j], acc[j]);
  }
#pragma unroll
  for (int j = 0; j < HID; ++j) myrow[j] = acc[j];      // raw fp32 out -> own LDS row
  __syncthreads();

  // coalesced bf16 shadow store
  {
    int rsub = lane >> 4, c4 = lane & 15;
    for (int r0 = 0; r0 < 64; r0 += 4) {
      int row = r0 + rsub;
      int g = nodeBase + row;
      if (g < N_NODES) {
        float4 f = *(const float4*)(P + row * LSTRIDE + c4 * 4);
        ushort4 v; v.x = f2bf(f.x); v.y = f2bf(f.y); v.z = f2bf(f.z); v.w = f2bf(f.w);
        *(ushort4*)(OUTB + (size_t)g * HID + c4 * 4) = v;
      }
    }
  }
  // fused BN stats (fp32, pre-rounding): per-wave column partials over valid rows
  int vcnt = N_NODES - nodeBase;
  if (vcnt > 64) vcnt = 64;
  if (vcnt < 0) vcnt = 0;
  float s = 0.f, q = 0.f;
  for (int r = 0; r < vcnt; ++r) {
    float v = P[r * LSTRIDE + lane];
    s += v; q += v * v;
  }
  part[waveIdx * 128 + lane] = s;
  part[waveIdx * 128 + 64 + lane] = q;
}

__global__ void k_bnparams(const float* __restrict__ part, float* __restrict__ sc,
                           const float* __restrict__ gamma, const float* __restrict__ beta) {
  __shared__ float red[8][128];
  int t = threadIdx.x;          // 1024 threads
  int col = t & 127, grp = t >> 7;
  float acc = 0.f;
  for (int b = grp; b < NPARTS; b += 8) acc += part[b * 128 + col];
  red[grp][col] = acc;
  __syncthreads();
  if (t < 128) {
    float tot = red[0][t] + red[1][t] + red[2][t] + red[3][t]
              + red[4][t] + red[5][t] + red[6][t] + red[7][t];
    red[0][t] = tot;
  }
  __syncthreads();
  if (t < 64) {
    float mean = red[0][t] * (1.0f / N_NODES);
    float var  = red[0][64 + t] * (1.0f / N_NODES) - mean * mean;
    float scale = gamma[t] * rsqrtf(var + BN_EPS);
    sc[t] = scale;
    sc[64 + t] = beta[t] - mean * scale;
  }
}

// ================= pooling + head (batch sorted -> segments) =================

__global__ void k_bounds(const int* __restrict__ batch, int* __restrict__ gstart) {
  int g = threadIdx.x;
  if (g > NUM_GRAPHS) return;
  int lo = 0, hi = N_NODES;
  while (lo < hi) {
    int mid = (lo + hi) >> 1;
    if (batch[mid] < g) lo = mid + 1; else hi = mid;
  }
  gstart[g] = lo;
}

__global__ void k_pool2(const u16* __restrict__ H, const int* __restrict__ gstart,
                        const float* __restrict__ sc, float* __restrict__ pooled) {
  int g = blockIdx.x;
  int s0 = gstart[g], s1 = gstart[g + 1];
  int wv = threadIdx.x >> 6, lane = threadIdx.x & 63;
  float scale = sc[lane], shift = sc[64 + lane];
  float acc = 0.f;
  for (int n = s0 + wv; n < s1; n += 4)
    acc += fmaxf(fmaf(bf2f(H[(size_t)n * HID + lane]), scale, shift), 0.f);
  __shared__ float ls[256];
  ls[threadIdx.x] = acc;
  __syncthreads();
  if (threadIdx.x < 64) {
    float v = ls[threadIdx.x] + ls[64 + threadIdx.x] + ls[128 + threadIdx.x] + ls[192 + threadIdx.x];
    float cnt = fmaxf((float)(s1 - s0), 1.0f);
    pooled[g * HID + threadIdx.x] = v / cnt;
  }
}

__global__ void k_final(const float* __restrict__ pooled,
                        const float* __restrict__ fw1, const float* __restrict__ fb1,
                        const float* __restrict__ fw2, const float* __restrict__ fb2,
                        float* __restrict__ out) {
  int g = blockIdx.x, t = threadIdx.x;
  __shared__ float row[64];
  row[t] = pooled[g * HID + t];
  __syncthreads();
  float acc = fb1[t];
  for (int k = 0; k < HID; ++k) acc = fmaf(row[k], fw1[k * HID + t], acc);
  float h = fmaxf(acc, 0.f);
  float v = h * fw2[t];
  for (int o = 32; o > 0; o >>= 1) v += __shfl_down(v, o);
  if (t == 0) out[g] = fmaxf(v + fb2[0], 0.f);
}

// ================= launch =================

extern "C" void kernel_launch(void* const* d_in, const int* in_sizes, int n_in,
                              void* d_out, int out_size, void* d_ws, size_t ws_size,
                              hipStream_t stream) {
  const float* x     = (const float*)d_in[0];
  const int*   ei    = (const int*)d_in[1];
  const int*   batch = (const int*)d_in[2];
  const int* esrc_in = ei;
  const int* edst_in = ei + N_EDGES;

  const float* w1[3], * b1[3], * w2[3], * b2[3], * gg[3], * bt[3];
  for (int l = 0; l < 3; ++l) {
    w1[l] = (const float*)d_in[3 + 6 * l];
    b1[l] = (const float*)d_in[4 + 6 * l];
    w2[l] = (const float*)d_in[5 + 6 * l];
    b2[l] = (const float*)d_in[6 + 6 * l];
    gg[l] = (const float*)d_in[7 + 6 * l];
    bt[l] = (const float*)d_in[8 + 6 * l];
  }
  const float* fw1 = (const float*)d_in[21];
  const float* fb1 = (const float*)d_in[22];
  const float* fw2 = (const float*)d_in[23];
  const float* fb2 = (const float*)d_in[24];

  char* p = (char*)d_ws;
  u16*   xb     = (u16*)p;     p += (size_t)N_NODES * HID * 2;   // 12.8 MB
  u16*   shA    = (u16*)p;     p += (size_t)N_NODES * HID * 2;   // 12.8 MB
  u16*   shB    = (u16*)p;     p += (size_t)N_NODES * HID * 2;   // 12.8 MB (bout overlay)
  int2*  bout   = (int2*)shB;                                    // dead before mlp L2 writes shB
  u16*   aggB   = (u16*)p;     p += (size_t)N_NODES * HID * 2;   // 12.8 MB
  int*   esrc   = (int*)p;     p += (size_t)N_EDGES * 4;         // 6.4 MB
  int*   deg    = (int*)p;     p += (size_t)N_NODES * 4;
  int*   off    = (int*)p;     p += 400016;
  int*   cur    = (int*)p;     p += (size_t)N_NODES * 4;
  int*   bsum   = (int*)p;     p += 2048;
  float* part   = (float*)p;   p += (size_t)NPARTS * 128 * 4;    // ~800 KB
  int*   blockHist = (int*)p;  p += PBLKS * 8 * 4;
  int*   blockBase = (int*)p;  p += PBLKS * 8 * 4;
  int*   bucketStart = (int*)p; p += 64;
  float* sc1    = (float*)p;   p += 512;
  float* sc2    = (float*)p;   p += 512;
  float* sc3    = (float*)p;   p += 512;
  float* pooled = (float*)p;   p += (size_t)NUM_GRAPHS * HID * 4;
  int*   gstart = (int*)p;     p += 1024;
  (void)ws_size; (void)in_sizes; (void)n_in; (void)out_size;

  // ---- CSR build ----
  k_pcount<<<PBLKS, 256, 0, stream>>>(edst_in, blockHist);
  k_p1scan<<<1, PBLKS, 0, stream>>>(blockHist, blockBase, bucketStart);
  k_part<<<PBLKS, 256, 0, stream>>>(esrc_in, edst_in, blockBase, bucketStart, bout);
  hipMemsetAsync(deg, 0, (size_t)N_NODES * 4, stream);
  k_deg2<<<2048, 256, 0, stream>>>(bout, bucketStart, deg);
  k_scan_block<<<NBLK_SCAN, 256, 0, stream>>>(deg, off, bsum);
  k_scan_tops<<<1, 512, 0, stream>>>(bsum);
  k_scan_add<<<NBLK_SCAN, 256, 0, stream>>>(deg, off, bsum, cur);
  k_fill2<<<2048, 256, 0, stream>>>(bout, bucketStart, cur, esrc);
  k_bounds<<<1, 192, 0, stream>>>(batch, gstart);
  k_tobf16<<<N_NODES * 16 / 256, 256, 0, stream>>>(x, xb);

  // ---- 3 GIN layers (BN fused into next gather / pooling; stats fused into MLP) ----
  k_gather<false><<<N_NODES * 64 / 256, 256, 0, stream>>>(xb, off, esrc, nullptr, aggB);
  k_mlp<<<MLP_BLKS, 128, 0, stream>>>(aggB, w1[0], b1[0], w2[0], b2[0], shA, part);
  k_bnparams<<<1, 1024, 0, stream>>>(part, sc1, gg[0], bt[0]);

  k_gather<true><<<N_NODES * 64 / 256, 256, 0, stream>>>(shA, off, esrc, sc1, aggB);
  k_mlp<<<MLP_BLKS, 128, 0, stream>>>(aggB, w1[1], b1[1], w2[1], b2[1], shB, part);
  k_bnparams<<<1, 1024, 0, stream>>>(part, sc2, gg[1], bt[1]);

  k_gather<true><<<N_NODES * 64 / 256, 256, 0, stream>>>(shB, off, esrc, sc2, aggB);
  k_mlp<<<MLP_BLKS, 128, 0, stream>>>(aggB, w1[2], b1[2], w2[2], b2[2], shA, part);
  k_bnparams<<<1, 1024, 0, stream>>>(part, sc3, gg[2], bt[2]);

  // ---- pool (BN fused) + head ----
  k_pool2<<<NUM_GRAPHS, 256, 0, stream>>>(shA, gstart, sc3, pooled);
  k_final<<<NUM_GRAPHS, 64, 0, stream>>>(pooled, fw1, fb1, fw2, fb2, (float*)d_out);
}

// Round 6
// 551.158 us; speedup vs baseline: 2.0231x; 1.2694x over previous
//
#include <hip/hip_runtime.h>

typedef unsigned short u16;
typedef unsigned int   u32;

#define N_NODES    100000
#define N_EDGES    1600000
#define HID        64
#define NUM_GRAPHS 128
#define BN_EPS     1e-5f

#define BSH        9                     // 512 nodes per bucket
#define NB         196                   // ceil(100000/512)
#define SC_T       2048                  // edges per scatter block
#define SC_NB      782                   // ceil(1600000/2048)
#define MAXBE      12288                 // LDS cap for edges/bucket (mean 8192, sigma ~90)

#define MLP_BLKS   782                   // ceil(100000/128)
#define NPARTS     (MLP_BLKS * 2)        // one partial per wave
#define LSTRIDE    65                    // padded LDS row stride (floats)

__device__ __forceinline__ float bf2f(u16 u) { return __uint_as_float(((u32)u) << 16); }
__device__ __forceinline__ u16 f2bf(float f) {           // RNE
  u32 u = __float_as_uint(f);
  u32 r = ((u >> 16) & 1u) + 0x7FFFu;
  return (u16)((u + r) >> 16);
}

// ================= CSR build v3: LDS counting-sort, streaming writes =================

// per-block 196-bucket histogram
__global__ void k_hist(const int* __restrict__ dst, int* __restrict__ blockHist) {
  __shared__ int h[NB];
  for (int i = threadIdx.x; i < NB; i += 256) h[i] = 0;
  __syncthreads();
  int base = blockIdx.x * SC_T;
  int cnt = min(SC_T, N_EDGES - base);
  for (int i = threadIdx.x; i < cnt; i += 256) atomicAdd(&h[dst[base + i] >> BSH], 1);
  __syncthreads();
  for (int i = threadIdx.x; i < NB; i += 256) blockHist[blockIdx.x * NB + i] = h[i];
}

// per-bucket exclusive scan over the 782 block counts
__global__ void k_hscan(const int* __restrict__ blockHist, int* __restrict__ blockBase,
                        int* __restrict__ bucketTot) {
  __shared__ int s[1024];
  int b = blockIdx.x, t = threadIdx.x;
  int v = (t < SC_NB) ? blockHist[t * NB + b] : 0;
  s[t] = v;
  __syncthreads();
  for (int d = 1; d < 1024; d <<= 1) {
    int x = (t >= d) ? s[t - d] : 0; __syncthreads();
    s[t] += x; __syncthreads();
  }
  if (t < SC_NB) blockBase[t * NB + b] = s[t] - v;
  if (t == 1023) bucketTot[b] = s[1023];
}

// bucket bases
__global__ void k_bscan(const int* __restrict__ bucketTot, int* __restrict__ bucketStart) {
  __shared__ int s[256];
  int t = threadIdx.x;
  int v = (t < NB) ? bucketTot[t] : 0;
  s[t] = v;
  __syncthreads();
  for (int d = 1; d < 256; d <<= 1) {
    int x = (t >= d) ? s[t - d] : 0; __syncthreads();
    s[t] += x; __syncthreads();
  }
  if (t < NB) bucketStart[t] = s[t] - v;
  if (t == NB - 1) bucketStart[NB] = s[t];
}

// LDS counting-sort per block, then coalesced run-writes into bucket regions (atomic-free)
__global__ __launch_bounds__(256) void k_scatter(
    const int* __restrict__ src, const int* __restrict__ dst,
    const int* __restrict__ blockBase, const int* __restrict__ bucketStart,
    int2* __restrict__ bout) {
  __shared__ int2 stage[SC_T];
  __shared__ int2 sorted[SC_T];
  __shared__ int lhist[NB], lscan[NB], lcur[NB];
  __shared__ int sbuf[256];
  int base = blockIdx.x * SC_T;
  int cnt = min(SC_T, N_EDGES - base);
  for (int i = threadIdx.x; i < NB; i += 256) lhist[i] = 0;
  __syncthreads();
  for (int i = threadIdx.x; i < cnt; i += 256) {
    int d = dst[base + i];
    stage[i] = make_int2(src[base + i], d);
    atomicAdd(&lhist[d >> BSH], 1);
  }
  __syncthreads();
  int t = threadIdx.x;
  int v = (t < NB) ? lhist[t] : 0;
  sbuf[t] = v;
  __syncthreads();
  for (int d = 1; d < 256; d <<= 1) {
    int x = (t >= d) ? sbuf[t - d] : 0; __syncthreads();
    sbuf[t] += x; __syncthreads();
  }
  if (t < NB) { lscan[t] = sbuf[t] - v; lcur[t] = sbuf[t] - v; }
  __syncthreads();
  for (int i = threadIdx.x; i < cnt; i += 256) {
    int2 e = stage[i];
    int pos = atomicAdd(&lcur[e.y >> BSH], 1);
    sorted[pos] = e;
  }
  __syncthreads();
  int bb = blockIdx.x * NB;
  for (int i = threadIdx.x; i < cnt; i += 256) {
    int2 e = sorted[i];
    int bk = e.y >> BSH;
    bout[bucketStart[bk] + blockBase[bb + bk] + (i - lscan[bk])] = e;
  }
}

// one block per bucket: build off + esrc entirely in LDS, stream out coalesced
__global__ __launch_bounds__(512) void k_build(
    const int2* __restrict__ bout, const int* __restrict__ bucketStart,
    int* __restrict__ off, int* __restrict__ esrc) {
  __shared__ int lcnt[512], ls[512], lcur[512];
  __shared__ int lout[MAXBE];
  int b = blockIdx.x;
  int node0 = b << BSH;
  int ncnt = min(512, N_NODES - node0);
  int e0 = bucketStart[b], e1 = bucketStart[b + 1];
  int t = threadIdx.x;
  lcnt[t] = 0;
  __syncthreads();
  for (int i = e0 + t; i < e1; i += 512) atomicAdd(&lcnt[bout[i].y - node0], 1);
  __syncthreads();
  int v = lcnt[t];
  ls[t] = v;
  __syncthreads();
  for (int d = 1; d < 512; d <<= 1) {
    int x = (t >= d) ? ls[t - d] : 0; __syncthreads();
    ls[t] += x; __syncthreads();
  }
  int excl = ls[t] - v;
  if (t < ncnt) off[node0 + t] = e0 + excl;
  if (b == NB - 1 && t == 0) off[N_NODES] = e1;
  lcur[t] = excl;
  __syncthreads();
  for (int i = e0 + t; i < e1; i += 512) {
    int2 e = bout[i];
    int pos = atomicAdd(&lcur[e.y - node0], 1);
    lout[pos] = e.x;
  }
  __syncthreads();
  int n = e1 - e0;
  for (int i = t; i < n; i += 512) esrc[e0 + i] = lout[i];
}

// ================= misc =================

__global__ void k_tobf16(const float* __restrict__ in, u16* __restrict__ out) {
  int i = blockIdx.x * blockDim.x + threadIdx.x;       // exact grid: N_NODES*16 chunks
  float4 v = ((const float4*)in)[i];
  ushort4 o;
  o.x = f2bf(v.x); o.y = f2bf(v.y); o.z = f2bf(v.z); o.w = f2bf(v.w);
  ((ushort4*)out)[i] = o;
}

// ================= per-layer kernels =================

// one wave per node, lane = feature; pull-gather over bf16 rows, fp32 accumulate.
template<bool BN>
__global__ void k_gather(const u16* __restrict__ Xb, const int* __restrict__ off,
                         const int* __restrict__ esrc, const float* __restrict__ sc,
                         u16* __restrict__ aggB) {
  int gid = blockIdx.x * blockDim.x + threadIdx.x;
  int w = gid >> 6;
  int t = gid & 63;
  if (w >= N_NODES) return;
  float scale = 1.f, shift = 0.f;
  if (BN) { scale = sc[t]; shift = sc[64 + t]; }
  int s0 = off[w], s1 = off[w + 1];
  float self = bf2f(Xb[(size_t)w * HID + t]);
  float acc = BN ? fmaxf(fmaf(self, scale, shift), 0.f) : self;
  int i = s0;
  for (; i + 8 <= s1; i += 8) {
    int n0 = esrc[i + 0], n1 = esrc[i + 1], n2 = esrc[i + 2], n3 = esrc[i + 3];
    int n4 = esrc[i + 4], n5 = esrc[i + 5], n6 = esrc[i + 6], n7 = esrc[i + 7];
    float v0 = bf2f(Xb[(size_t)n0 * HID + t]);
    float v1 = bf2f(Xb[(size_t)n1 * HID + t]);
    float v2 = bf2f(Xb[(size_t)n2 * HID + t]);
    float v3 = bf2f(Xb[(size_t)n3 * HID + t]);
    float v4 = bf2f(Xb[(size_t)n4 * HID + t]);
    float v5 = bf2f(Xb[(size_t)n5 * HID + t]);
    float v6 = bf2f(Xb[(size_t)n6 * HID + t]);
    float v7 = bf2f(Xb[(size_t)n7 * HID + t]);
    if (BN) {
      v0 = fmaxf(fmaf(v0, scale, shift), 0.f);
      v1 = fmaxf(fmaf(v1, scale, shift), 0.f);
      v2 = fmaxf(fmaf(v2, scale, shift), 0.f);
      v3 = fmaxf(fmaf(v3, scale, shift), 0.f);
      v4 = fmaxf(fmaf(v4, scale, shift), 0.f);
      v5 = fmaxf(fmaf(v5, scale, shift), 0.f);
      v6 = fmaxf(fmaf(v6, scale, shift), 0.f);
      v7 = fmaxf(fmaf(v7, scale, shift), 0.f);
    }
    acc += ((v0 + v1) + (v2 + v3)) + ((v4 + v5) + (v6 + v7));
  }
  for (; i + 4 <= s1; i += 4) {
    int n0 = esrc[i + 0], n1 = esrc[i + 1], n2 = esrc[i + 2], n3 = esrc[i + 3];
    float v0 = bf2f(Xb[(size_t)n0 * HID + t]);
    float v1 = bf2f(Xb[(size_t)n1 * HID + t]);
    float v2 = bf2f(Xb[(size_t)n2 * HID + t]);
    float v3 = bf2f(Xb[(size_t)n3 * HID + t]);
    if (BN) {
      v0 = fmaxf(fmaf(v0, scale, shift), 0.f);
      v1 = fmaxf(fmaf(v1, scale, shift), 0.f);
      v2 = fmaxf(fmaf(v2, scale, shift), 0.f);
      v3 = fmaxf(fmaf(v3, scale, shift), 0.f);
    }
    acc += (v0 + v1) + (v2 + v3);
  }
  for (; i < s1; ++i) {
    float v = bf2f(Xb[(size_t)esrc[i] * HID + t]);
    if (BN) v = fmaxf(fmaf(v, scale, shift), 0.f);
    acc += v;
  }
  aggB[(size_t)w * HID + t] = f2bf(acc);
}

// Fused 2-layer MLP: bf16 agg -> fp32 LDS panel; accumulators static in VGPRs;
// bf16 shadow out; fp32 BN column-stat partials fused in epilogue.
__global__ __launch_bounds__(128, 2) void k_mlp(
    const u16* __restrict__ AGGB,
    const float* __restrict__ w1, const float* __restrict__ b1,
    const float* __restrict__ w2, const float* __restrict__ b2,
    u16* __restrict__ OUTB, float* __restrict__ part) {
  __shared__ float panel[2][64 * LSTRIDE];
  int wv = threadIdx.x >> 6, lane = threadIdx.x & 63;
  float* P = panel[wv];
  int waveIdx = blockIdx.x * 2 + wv;
  int nodeBase = waveIdx * 64;

  {
    int rsub = lane >> 4, c4 = lane & 15;
    for (int r0 = 0; r0 < 64; r0 += 4) {
      int row = r0 + rsub;
      int g = nodeBase + row; if (g > N_NODES - 1) g = N_NODES - 1;
      ushort4 v = *(const ushort4*)(AGGB + (size_t)g * HID + c4 * 4);
      float4 f; f.x = bf2f(v.x); f.y = bf2f(v.y); f.z = bf2f(v.z); f.w = bf2f(v.w);
      *(float4*)(P + row * LSTRIDE + c4 * 4) = f;
    }
  }
  __syncthreads();

  float* myrow = P + lane * LSTRIDE;
  float acc[HID];
#pragma unroll
  for (int j = 0; j < HID; ++j) acc[j] = b1[j];
  for (int k = 0; k < HID; ++k) {
    float xv = myrow[k];
    const float* wr = w1 + k * HID;
#pragma unroll
    for (int j = 0; j < HID; ++j) acc[j] = fmaf(xv, wr[j], acc[j]);
  }
#pragma unroll
  for (int j = 0; j < HID; ++j) myrow[j] = fmaxf(acc[j], 0.f);
#pragma unroll
  for (int j = 0; j < HID; ++j) acc[j] = b2[j];
  for (int k = 0; k < HID; ++k) {
    float hv = myrow[k];
    const float* wr = w2 + k * HID;
#pragma unroll
    for (int j = 0; j < HID; ++j) acc[j] = fmaf(hv, wr[j], acc[j]);
  }
#pragma unroll
  for (int j = 0; j < HID; ++j) myrow[j] = acc[j];
  __syncthreads();

  {
    int rsub = lane >> 4, c4 = lane & 15;
    for (int r0 = 0; r0 < 64; r0 += 4) {
      int row = r0 + rsub;
      int g = nodeBase + row;
      if (g < N_NODES) {
        float4 f = *(const float4*)(P + row * LSTRIDE + c4 * 4);
        ushort4 v; v.x = f2bf(f.x); v.y = f2bf(f.y); v.z = f2bf(f.z); v.w = f2bf(f.w);
        *(ushort4*)(OUTB + (size_t)g * HID + c4 * 4) = v;
      }
    }
  }
  int vcnt = N_NODES - nodeBase;
  if (vcnt > 64) vcnt = 64;
  if (vcnt < 0) vcnt = 0;
  float s = 0.f, q = 0.f;
  for (int r = 0; r < vcnt; ++r) {
    float v = P[r * LSTRIDE + lane];
    s += v; q += v * v;
  }
  part[waveIdx * 128 + lane] = s;
  part[waveIdx * 128 + 64 + lane] = q;
}

__global__ void k_bnparams(const float* __restrict__ part, float* __restrict__ sc,
                           const float* __restrict__ gamma, const float* __restrict__ beta) {
  __shared__ float red[8][128];
  int t = threadIdx.x;          // 1024 threads
  int col = t & 127, grp = t >> 7;
  float acc = 0.f;
  for (int b = grp; b < NPARTS; b += 8) acc += part[b * 128 + col];
  red[grp][col] = acc;
  __syncthreads();
  if (t < 128) {
    float tot = red[0][t] + red[1][t] + red[2][t] + red[3][t]
              + red[4][t] + red[5][t] + red[6][t] + red[7][t];
    red[0][t] = tot;
  }
  __syncthreads();
  if (t < 64) {
    float mean = red[0][t] * (1.0f / N_NODES);
    float var  = red[0][64 + t] * (1.0f / N_NODES) - mean * mean;
    float scale = gamma[t] * rsqrtf(var + BN_EPS);
    sc[t] = scale;
    sc[64 + t] = beta[t] - mean * scale;
  }
}

// ================= pooling + head (batch sorted -> segments) =================

__global__ void k_bounds(const int* __restrict__ batch, int* __restrict__ gstart) {
  int g = threadIdx.x;
  if (g > NUM_GRAPHS) return;
  int lo = 0, hi = N_NODES;
  while (lo < hi) {
    int mid = (lo + hi) >> 1;
    if (batch[mid] < g) lo = mid + 1; else hi = mid;
  }
  gstart[g] = lo;
}

__global__ void k_pool2(const u16* __restrict__ H, const int* __restrict__ gstart,
                        const float* __restrict__ sc, float* __restrict__ pooled) {
  int g = blockIdx.x;
  int s0 = gstart[g], s1 = gstart[g + 1];
  int wv = threadIdx.x >> 6, lane = threadIdx.x & 63;
  float scale = sc[lane], shift = sc[64 + lane];
  float acc = 0.f;
  for (int n = s0 + wv; n < s1; n += 4)
    acc += fmaxf(fmaf(bf2f(H[(size_t)n * HID + lane]), scale, shift), 0.f);
  __shared__ float ls[256];
  ls[threadIdx.x] = acc;
  __syncthreads();
  if (threadIdx.x < 64) {
    float v = ls[threadIdx.x] + ls[64 + threadIdx.x] + ls[128 + threadIdx.x] + ls[192 + threadIdx.x];
    float cnt = fmaxf((float)(s1 - s0), 1.0f);
    pooled[g * HID + threadIdx.x] = v / cnt;
  }
}

__global__ void k_final(const float* __restrict__ pooled,
                        const float* __restrict__ fw1, const float* __restrict__ fb1,
                        const float* __restrict__ fw2, const float* __restrict__ fb2,
                        float* __restrict__ out) {
  int g = blockIdx.x, t = threadIdx.x;
  __shared__ float row[64];
  row[t] = pooled[g * HID + t];
  __syncthreads();
  float acc = fb1[t];
  for (int k = 0; k < HID; ++k) acc = fmaf(row[k], fw1[k * HID + t], acc);
  float h = fmaxf(acc, 0.f);
  float v = h * fw2[t];
  for (int o = 32; o > 0; o >>= 1) v += __shfl_down(v, o);
  if (t == 0) out[g] = fmaxf(v + fb2[0], 0.f);
}

// ================= launch =================

extern "C" void kernel_launch(void* const* d_in, const int* in_sizes, int n_in,
                              void* d_out, int out_size, void* d_ws, size_t ws_size,
                              hipStream_t stream) {
  const float* x     = (const float*)d_in[0];
  const int*   ei    = (const int*)d_in[1];
  const int*   batch = (const int*)d_in[2];
  const int* esrc_in = ei;
  const int* edst_in = ei + N_EDGES;

  const float* w1[3], * b1[3], * w2[3], * b2[3], * gg[3], * bt[3];
  for (int l = 0; l < 3; ++l) {
    w1[l] = (const float*)d_in[3 + 6 * l];
    b1[l] = (const float*)d_in[4 + 6 * l];
    w2[l] = (const float*)d_in[5 + 6 * l];
    b2[l] = (const float*)d_in[6 + 6 * l];
    gg[l] = (const float*)d_in[7 + 6 * l];
    bt[l] = (const float*)d_in[8 + 6 * l];
  }
  const float* fw1 = (const float*)d_in[21];
  const float* fb1 = (const float*)d_in[22];
  const float* fw2 = (const float*)d_in[23];
  const float* fb2 = (const float*)d_in[24];

  char* p = (char*)d_ws;
  u16*   xb     = (u16*)p;     p += (size_t)N_NODES * HID * 2;   // 12.8 MB
  u16*   shA    = (u16*)p;     p += (size_t)N_NODES * HID * 2;   // 12.8 MB
  u16*   shB    = (u16*)p;     p += (size_t)N_NODES * HID * 2;   // 12.8 MB (bout overlay)
  int2*  bout   = (int2*)shB;                                    // dead before mlp L2 writes shB
  u16*   aggB   = (u16*)p;     p += (size_t)N_NODES * HID * 2;   // 12.8 MB
  int*   esrc   = (int*)p;     p += (size_t)N_EDGES * 4;         // 6.4 MB
  int*   off    = (int*)p;     p += 400016;                      // N_NODES+1 ints
  float* part   = (float*)p;   p += (size_t)NPARTS * 128 * 4;    // ~800 KB
  int*   blockHist = (int*)p;  p += (size_t)SC_NB * NB * 4;      // 613 KB
  int*   blockBase = (int*)p;  p += (size_t)SC_NB * NB * 4;      // 613 KB
  int*   bucketTot = (int*)p;  p += 1024;
  int*   bucketStart = (int*)p; p += 1024;                       // NB+1 ints
  float* sc1    = (float*)p;   p += 512;
  float* sc2    = (float*)p;   p += 512;
  float* sc3    = (float*)p;   p += 512;
  float* pooled = (float*)p;   p += (size_t)NUM_GRAPHS * HID * 4;
  int*   gstart = (int*)p;     p += 1024;
  (void)ws_size; (void)in_sizes; (void)n_in; (void)out_size;

  // ---- CSR build v3 ----
  k_hist<<<SC_NB, 256, 0, stream>>>(edst_in, blockHist);
  k_hscan<<<NB, 1024, 0, stream>>>(blockHist, blockBase, bucketTot);
  k_bscan<<<1, 256, 0, stream>>>(bucketTot, bucketStart);
  k_scatter<<<SC_NB, 256, 0, stream>>>(esrc_in, edst_in, blockBase, bucketStart, bout);
  k_build<<<NB, 512, 0, stream>>>(bout, bucketStart, off, esrc);
  k_bounds<<<1, 192, 0, stream>>>(batch, gstart);
  k_tobf16<<<N_NODES * 16 / 256, 256, 0, stream>>>(x, xb);

  // ---- 3 GIN layers (BN fused into next gather / pooling; stats fused into MLP) ----
  k_gather<false><<<N_NODES * 64 / 256, 256, 0, stream>>>(xb, off, esrc, nullptr, aggB);
  k_mlp<<<MLP_BLKS, 128, 0, stream>>>(aggB, w1[0], b1[0], w2[0], b2[0], shA, part);
  k_bnparams<<<1, 1024, 0, stream>>>(part, sc1, gg[0], bt[0]);

  k_gather<true><<<N_NODES * 64 / 256, 256, 0, stream>>>(shA, off, esrc, sc1, aggB);
  k_mlp<<<MLP_BLKS, 128, 0, stream>>>(aggB, w1[1], b1[1], w2[1], b2[1], shB, part);
  k_bnparams<<<1, 1024, 0, stream>>>(part, sc2, gg[1], bt[1]);

  k_gather<true><<<N_NODES * 64 / 256, 256, 0, stream>>>(shB, off, esrc, sc2, aggB);
  k_mlp<<<MLP_BLKS, 128, 0, stream>>>(aggB, w1[2], b1[2], w2[2], b2[2], shA, part);
  k_bnparams<<<1, 1024, 0, stream>>>(part, sc3, gg[2], bt[2]);

  // ---- pool (BN fused) + head ----
  k_pool2<<<NUM_GRAPHS, 256, 0, stream>>>(shA, gstart, sc3, pooled);
  k_final<<<NUM_GRAPHS, 64, 0, stream>>>(pooled, fw1, fb1, fw2, fb2, (float*)d_out);
}